// Round 5
// baseline (1557.834 us; speedup 1.0000x reference)
//
#include <hip/hip_runtime.h>
#include <hip/hip_bf16.h>

typedef __attribute__((ext_vector_type(8))) __bf16 bf16x8;
typedef __attribute__((ext_vector_type(4))) __bf16 bf16x4;
typedef __attribute__((ext_vector_type(4))) float  f32x4;

#define DIM   2304
#define NH    24
#define HD    96
#define SPS   512

#define SBAR() __builtin_amdgcn_sched_barrier(0)
#define BARR() __builtin_amdgcn_s_barrier()
#define LGKM(n) asm volatile("s_waitcnt lgkmcnt(%0)" :: "n"(n) : "memory")
#define VMC(n)  asm volatile("s_waitcnt vmcnt(%0)"  :: "n"(n) : "memory")

// ---- async global->LDS, 16B per lane (dest = wave-uniform base + lane*16) ----
__device__ __forceinline__ void gload16(const void* gp, void* lp) {
  __builtin_amdgcn_global_load_lds(
      (__attribute__((address_space(1))) void*)(unsigned long long)gp,
      (__attribute__((address_space(3))) void*)lp, 16, 0, 0);
}

// ---- weight transpose + bf16 cast: dst[n][k] = (bf16) src[k][n] ----
__global__ __launch_bounds__(256) void pack_w_kernel(
    const float* __restrict__ wq, const float* __restrict__ wk,
    const float* __restrict__ wv, const float* __restrict__ wo,
    __bf16* __restrict__ dqkv, __bf16* __restrict__ dwo)
{
  __shared__ float t[64][65];
  const int z = blockIdx.z;
  const float* src = (z == 0) ? wq : (z == 1) ? wk : (z == 2) ? wv : wo;
  __bf16* dst = (z < 3) ? (dqkv + (size_t)z * DIM * DIM) : dwo;
  const int n0 = blockIdx.x * 64, k0 = blockIdx.y * 64;
  const int tx = threadIdx.x & 63, ty = threadIdx.x >> 6;
#pragma unroll
  for (int j = 0; j < 64; j += 4)
    t[ty + j][tx] = src[(size_t)(k0 + ty + j) * DIM + n0 + tx];
  __syncthreads();
#pragma unroll
  for (int j = 0; j < 64; j += 4)
    dst[(size_t)(n0 + ty + j) * DIM + k0 + tx] = (__bf16)t[tx][ty + j];
}

// ---- hidden_states fp32 -> bf16 ----
__global__ __launch_bounds__(256) void pack_hs_kernel(
    const float4* __restrict__ src, bf16x4* __restrict__ dst)
{
  const int i = blockIdx.x * 256 + threadIdx.x;
  const float4 f = src[i];
  bf16x4 o = { (__bf16)f.x, (__bf16)f.y, (__bf16)f.z, (__bf16)f.w };
  dst[i] = o;
}

// ====== 8-phase GEMM, counted vmcnt AND counted lgkm (read-ahead) pipeline ======
// A [M][K], B [N][K] row-major bf16. 512 thr = 8 waves (2M x 4N), BK=64,
// XOR-swizzled LDS both-sides. Fragment ds_reads are issued ONE PHASE EARLY into
// ping/pong register sets and waited with counted lgkmcnt, so LDS-read data
// movement overlaps the previous phase's MFMA cluster (lgkm analog of T4).
// Stage placement vs WAR: stage-B(t+2) after P2's barrier (RB1(t) retired by all
// waves), stage-A(t+2) after P3's barrier (RA1(t) retired). Cross-tile reads in
// P2 after vmcnt(4)+barrier (drains stage(t+1), leaves stage(t+2)-B in flight).

template<int NJ>
__device__ __forceinline__ void stage_half(
    const __bf16* __restrict__ X, __bf16* lX, int r0, int k0,
    int srow, int schunk, int dslot)
{
#pragma unroll
  for (int j = 0; j < NJ; ++j)
    gload16(X + (size_t)(r0 + j * 64 + srow) * DIM + k0 + schunk,
            lX + (j * 64 + srow) * 64 + dslot);
}

template<int EPI>
__global__ __launch_bounds__(512, 1) void gemm8p_kernel(
    const __bf16* __restrict__ A, const __bf16* __restrict__ B,
    const float* __restrict__ b0, const float* __restrict__ b1v, const float* __restrict__ b2,
    __bf16* __restrict__ o0, __bf16* __restrict__ o1, __bf16* __restrict__ o2,
    float* __restrict__ fout)
{
  constexpr int MF = (EPI == 0) ? 4 : 2;         // A fragments per half
  constexpr int MROWS = MF * 64;                 // 256 or 128
  constexpr int AL = 2 * MF;                     // ds_reads per A-half
  constexpr int L_P0 = AL + 4;                   // leaves RB1(4)+RA1(AL)
  constexpr int L_P1 = AL;                       // leaves RA1
  constexpr int L_P2 = AL + 4;                   // leaves RA0'(AL)+RB0'(4)
  constexpr int V_PRO = MF + 4;                  // prologue: drain stage(0)

  __shared__ __align__(16) __bf16 As[2][MROWS * 64];
  __shared__ __align__(16) __bf16 Bs[2][256 * 64];
  __shared__ float tcos[640], tsin[640];
  const int tid = threadIdx.x;
  if (EPI == 0) {
    for (int i = tid; i < 640; i += 512) {
      int pos, jj = i & 15;
      if (i < 128)      pos = i >> 4;
      else if (i < 384) pos = (i - 128) >> 4;
      else              pos = (i - 384) >> 4;
      const float invf = exp2f(-(float)jj * 0.83048202372184059f); // 10000^(-jj/16)
      float s, c;
      sincosf((float)pos * invf, &s, &c);
      tcos[i] = c; tsin[i] = s;
    }
    LGKM(0);   // keep table ds_writes out of the K-loop lgkm accounting
  }
  const int wid = tid >> 6, l = tid & 63;
  const int lq = l & 15, lg = l >> 4;
  const int wm = wid >> 2, wn = wid & 3;
  const int bid = blockIdx.x;
  const int xcd = bid & 7, local = bid >> 3;
  int m0, n0;
  if (EPI == 0) {                                 // 864 blocks: 32 m x 27 n
    m0 = (xcd * 4 + (local & 3)) * 256;
    n0 = (local >> 2) * 256;
  } else {                                        // 576 blocks: 64 m x 9 n
    m0 = (xcd * 8 + (local & 7)) * 128;
    n0 = (local >> 3) * 256;
  }
  const int srow = tid >> 3;
  const int schunk = ((tid & 7) ^ (srow & 7)) * 8;
  const int dslot = (tid & 7) * 8;
  const int laneA0 = lq * 128 + ((lg * 16) ^ ((lq & 7) << 4));
  const int laneA1 = lq * 128 + ((64 + lg * 16) ^ ((lq & 7) << 4));

  f32x4 acc[2 * MF][4] = {};
  bf16x8 aX[MF][2], aY[MF][2], b0A[2][2], b0B[2][2], b1[2][2];

#define LOAD_A(dst, bufp, Hh) do { _Pragma("unroll")                            \
  for (int fm = 0; fm < MF; ++fm) {                                             \
    dst[fm][0] = *(const bf16x8*)((bufp) + (wm * (MF * 32) + (Hh) * (MF * 16) + fm * 16) * 128 + laneA0); \
    dst[fm][1] = *(const bf16x8*)((bufp) + (wm * (MF * 32) + (Hh) * (MF * 16) + fm * 16) * 128 + laneA1); } } while (0)

#define LOAD_B(dst, bufp, Qq) do { _Pragma("unroll")                            \
  for (int fn = 0; fn < 2; ++fn) {                                              \
    dst[fn][0] = *(const bf16x8*)((bufp) + (wn * 64 + (Qq) * 32 + fn * 16) * 128 + laneA0); \
    dst[fn][1] = *(const bf16x8*)((bufp) + (wn * 64 + (Qq) * 32 + fn * 16) * 128 + laneA1); } } while (0)

#define MFMA8(aset, bset, Hh, Qq) do {                                          \
  __builtin_amdgcn_s_setprio(1); _Pragma("unroll")                              \
  for (int fm = 0; fm < MF; ++fm) _Pragma("unroll")                             \
    for (int fn = 0; fn < 2; ++fn) _Pragma("unroll")                            \
      for (int kk = 0; kk < 2; ++kk)                                            \
        acc[(Hh) * MF + fm][(Qq) * 2 + fn] = __builtin_amdgcn_mfma_f32_16x16x32_bf16( \
            aset[fm][kk], bset[fn][kk], acc[(Hh) * MF + fm][(Qq) * 2 + fn], 0, 0, 0); \
  __builtin_amdgcn_s_setprio(0); } while (0)

  // prologue: stage tiles 0,1; issue tile-0 fragment reads (RA0, RB0, RB1)
  stage_half<MF>(A, As[0], m0, 0, srow, schunk, dslot);
  stage_half<4>(B, Bs[0], n0, 0, srow, schunk, dslot);
  stage_half<MF>(A, As[1], m0, 64, srow, schunk, dslot);
  stage_half<4>(B, Bs[1], n0, 64, srow, schunk, dslot);
  VMC(V_PRO);                       // tile-0 staged; stage(1) stays in flight
  BARR();
  const char* a0p = (const char*)&As[0][0];
  const char* b0p = (const char*)&Bs[0][0];
  const char* a1p = (const char*)&As[1][0];
  const char* b1p = (const char*)&Bs[1][0];
  LOAD_A(aX, a0p, 0);
  LOAD_B(b0A, b0p, 0);
  LOAD_B(b1, b0p, 1);
  SBAR();

// steady tile: phases P0..P3; reads for phase p+1 issued in phase p.
#define STEADY_TILE(ACURP, BCURP, ANXTP, BNXTP, SADST, SBDST, B0CUR, B0NXT, KNOFF, DOSTG, GATEN) \
  BARR(); LOAD_A(aY, ACURP, 1); SBAR(); LGKM(L_P0); SBAR(); MFMA8(aX, B0CUR, 0, 0);  \
  BARR(); SBAR(); LGKM(L_P1); SBAR(); MFMA8(aX, b1, 0, 1);                            \
  BARR();                                                                              \
  if (DOSTG) stage_half<4>(B, SBDST, n0, KNOFF, srow, schunk, dslot);                  \
  VMC(GATEN); BARR();                                                                  \
  LOAD_A(aX, ANXTP, 0); LOAD_B(B0NXT, BNXTP, 0); SBAR(); LGKM(L_P2); SBAR();           \
  MFMA8(aY, b1, 1, 1);                                                                 \
  BARR();                                                                              \
  if (DOSTG) stage_half<MF>(A, SADST, m0, KNOFF, srow, schunk, dslot);                 \
  LOAD_B(b1, BNXTP, 1); SBAR(); MFMA8(aY, B0CUR, 1, 0);

#define FINAL_TILE(ACURP, B0CUR)                                                      \
  BARR(); LOAD_A(aY, ACURP, 1); SBAR(); LGKM(L_P0); SBAR(); MFMA8(aX, B0CUR, 0, 0);  \
  BARR(); SBAR(); LGKM(L_P1); SBAR(); MFMA8(aX, b1, 0, 1);                            \
  BARR(); SBAR(); LGKM(0); SBAR(); MFMA8(aY, b1, 1, 1);                               \
  BARR(); SBAR(); MFMA8(aY, B0CUR, 1, 0);

  for (int tt = 0; tt < 34; tt += 2) {
    STEADY_TILE(a0p, b0p, a1p, b1p, As[0], Bs[0], b0A, b0B, (tt + 2) * 64, 1, 4)
    STEADY_TILE(a1p, b1p, a0p, b0p, As[1], Bs[1], b0B, b0A, (tt + 3) * 64, 1, 4)
  }
  // t = 34: no staging left; gate drains everything before reading tile 35
  STEADY_TILE(a0p, b0p, a1p, b1p, As[0], Bs[0], b0A, b0B, 0, 0, 0)
  // t = 35
  FINAL_TILE(a1p, b0B)

#undef STEADY_TILE
#undef FINAL_TILE
#undef LOAD_A
#undef LOAD_B
#undef MFMA8

  if (EPI == 0) {
    const int mat = n0 / DIM;
    const int nb = n0 - mat * DIM;
    const float* bias = (mat == 0) ? b0 : (mat == 1) ? b1v : b2;
    __bf16* outp = (mat == 0) ? o0 : (mat == 1) ? o1 : o2;
#pragma unroll
    for (int mr = 0; mr < 2 * MF; ++mr) {
      const int gq = (m0 + wm * 128 + mr * 16) >> 4;
      const int si = gq * 4 + lg;
      const int pos3[3] = { si >> 8, (si >> 4) & 15, si & 15 };
#pragma unroll
      for (int p = 0; p < 2; ++p) {
        const int nlo = nb + wn * 64 + (2 * p) * 16 + lq;
        const int nhi = nlo + 16;
        const int hlo = nlo / HD, dlo = nlo - hlo * HD;
        const int hhi = nhi / HD, dhi = nhi - hhi * HD;
        const float blo = bias[nlo], bhi = bias[nhi];
        float c = 1.f, s = 0.f;
        if (mat < 2) {
          const int cix = dlo >> 5;
          const int toff = ((cix == 0) ? 0 : (cix == 1) ? 128 : 384) + pos3[cix] * 16 + lq;
          c = tcos[toff]; s = tsin[toff];
        }
#pragma unroll
        for (int r = 0; r < 4; ++r) {
          const int bp = lg * 4 + r;
          const float x1 = acc[mr][2 * p][r] + blo;
          const float x2 = acc[mr][2 * p + 1][r] + bhi;
          float y1 = x1, y2 = x2;
          if (mat < 2) { y1 = x1 * c - x2 * s; y2 = x2 * c + x1 * s; }
          outp[((size_t)(bp * NH + hlo) * SPS + gq) * HD + dlo] = (__bf16)y1;
          outp[((size_t)(bp * NH + hhi) * SPS + gq) * HD + dhi] = (__bf16)y2;
        }
      }
    }
  } else {
#pragma unroll
    for (int mr = 0; mr < 2 * MF; ++mr) {
      const int rbase = m0 + wm * 64 + mr * 16;
#pragma unroll
      for (int nr = 0; nr < 4; ++nr) {
        const int n = n0 + wn * 64 + nr * 16 + lq;
        const float bia = b0[n];
#pragma unroll
        for (int r = 0; r < 4; ++r)
          fout[(size_t)(rbase + lg * 4 + r) * DIM + n] = acc[mr][nr][r] + bia;
      }
    }
  }
}

// ---- flash attention: 4 waves x 16 q-rows; XCD-chunked grid so the 8 q-tile
//      blocks of one (bp,h) share an XCD's L2 (KV fetched once, not 8x) ----
__global__ __launch_bounds__(256) void attn_kernel(
    const __bf16* __restrict__ q, const __bf16* __restrict__ k,
    const __bf16* __restrict__ v, __bf16* __restrict__ ao)
{
  __shared__ __bf16 Vt[96 * 72];        // V^T tile [d][key], padded rows
  __shared__ __bf16 Pl[4][16 * 72];     // per-wave P [q][key], padded rows
  const int tid = threadIdx.x;
  const int w = tid >> 6, l = tid & 63;
  const int lq = l & 15, lg = l >> 4;
  const int bid = blockIdx.x;
  const int swz = (bid & 7) * 384 + (bid >> 3);
  const int qt = swz & 7;
  const int h  = (swz >> 3) % NH;
  const int bp = swz / (NH * 8);
  const size_t bh = ((size_t)bp * NH + h) * SPS;
  const __bf16* qb = q + bh * HD;
  const __bf16* kb = k + bh * HD;
  const __bf16* vb = v + bh * HD;
  bf16x8 qf[3];
  {
    const __bf16* qr = qb + (size_t)(qt * 64 + w * 16 + lq) * HD + lg * 8;
    qf[0] = *(const bf16x8*)(qr);
    qf[1] = *(const bf16x8*)(qr + 32);
    qf[2] = *(const bf16x8*)(qr + 64);
  }
  const float sc = 0.10206207261596575f * 1.4426950408889634f; // 96^-0.5 * log2(e)
  float m_run = -1e30f, l_run = 0.f;
  f32x4 o[6] = {};
  for (int kb0 = 0; kb0 < SPS; kb0 += 64) {
    __syncthreads();
#pragma unroll
    for (int p = 0; p < 3; ++p) {        // cooperative V^T staging
      const int lin = p * 256 + tid;
      const int row = lin / 12, c8 = (lin % 12) * 8;
      bf16x8 vv = *(const bf16x8*)(vb + (size_t)(kb0 + row) * HD + c8);
#pragma unroll
      for (int j = 0; j < 8; ++j) Vt[(c8 + j) * 72 + row] = vv[j];
    }
    __syncthreads();
    f32x4 st[4];
#pragma unroll
    for (int t2 = 0; t2 < 4; ++t2) {
      const __bf16* kr = kb + (size_t)(kb0 + t2 * 16 + lq) * HD + lg * 8;
      bf16x8 k0f = *(const bf16x8*)(kr);
      bf16x8 k1f = *(const bf16x8*)(kr + 32);
      bf16x8 k2f = *(const bf16x8*)(kr + 64);
      f32x4 s = {};
      s = __builtin_amdgcn_mfma_f32_16x16x32_bf16(k0f, qf[0], s, 0, 0, 0);
      s = __builtin_amdgcn_mfma_f32_16x16x32_bf16(k1f, qf[1], s, 0, 0, 0);
      s = __builtin_amdgcn_mfma_f32_16x16x32_bf16(k2f, qf[2], s, 0, 0, 0);
      st[t2] = s;
    }
    float tmax = -1e30f;
#pragma unroll
    for (int t2 = 0; t2 < 4; ++t2)
#pragma unroll
      for (int r = 0; r < 4; ++r) tmax = fmaxf(tmax, st[t2][r]);
    tmax = fmaxf(tmax, __shfl_xor(tmax, 16));
    tmax = fmaxf(tmax, __shfl_xor(tmax, 32));
    tmax *= sc;
    const float m_new = fmaxf(m_run, tmax);
    const float alpha = exp2f(m_run - m_new);
    float tsum = 0.f;
#pragma unroll
    for (int t2 = 0; t2 < 4; ++t2) {
      bf16x4 pb;
#pragma unroll
      for (int r = 0; r < 4; ++r) {
        const float p = exp2f(st[t2][r] * sc - m_new);
        tsum += p;
        pb[r] = (__bf16)p;
      }
      *(bf16x4*)&Pl[w][lq * 72 + t2 * 16 + lg * 4] = pb;
    }
    tsum += __shfl_xor(tsum, 16);
    tsum += __shfl_xor(tsum, 32);
    l_run = l_run * alpha + tsum;
    m_run = m_new;
    float al[4];
#pragma unroll
    for (int r = 0; r < 4; ++r) al[r] = __shfl(alpha, lg * 4 + r);
#pragma unroll
    for (int ni = 0; ni < 6; ++ni)
#pragma unroll
      for (int r = 0; r < 4; ++r) o[ni][r] *= al[r];
#pragma unroll
    for (int ks = 0; ks < 2; ++ks) {
      bf16x8 pa = *(const bf16x8*)&Pl[w][lq * 72 + ks * 32 + lg * 8];
#pragma unroll
      for (int ni = 0; ni < 6; ++ni) {
        bf16x8 vf = *(const bf16x8*)&Vt[(ni * 16 + lq) * 72 + ks * 32 + lg * 8];
        o[ni] = __builtin_amdgcn_mfma_f32_16x16x32_bf16(pa, vf, o[ni], 0, 0, 0);
      }
    }
  }
  float linv[4];
#pragma unroll
  for (int r = 0; r < 4; ++r) linv[r] = 1.f / __shfl(l_run, lg * 4 + r);
#pragma unroll
  for (int ni = 0; ni < 6; ++ni)
#pragma unroll
    for (int r = 0; r < 4; ++r) {
      const int gq = qt * 64 + w * 16 + lg * 4 + r;
      const int d = ni * 16 + lq;
      ao[(size_t)(gq * 16 + bp) * DIM + h * HD + d] = (__bf16)(o[ni][r] * linv[r]);
    }
}

extern "C" void kernel_launch(void* const* d_in, const int* in_sizes, int n_in,
                              void* d_out, int out_size, void* d_ws, size_t ws_size,
                              hipStream_t stream) {
  const float* hs = (const float*)d_in[0];
  const float* wq = (const float*)d_in[1];
  const float* bq = (const float*)d_in[2];
  const float* wk = (const float*)d_in[3];
  const float* bk = (const float*)d_in[4];
  const float* wv = (const float*)d_in[5];
  const float* bv = (const float*)d_in[6];
  const float* wo = (const float*)d_in[7];
  const float* bo = (const float*)d_in[8];
  float* out = (float*)d_out;

  char* ws = (char*)d_ws;
  __bf16* wqkvT = (__bf16*)(ws);                               // 31,850,496
  __bf16* woT   = (__bf16*)(ws + 31850496);                    // 10,616,832
  __bf16* hsb   = (__bf16*)(ws + 42467328);                    // 37,748,736
  __bf16* qb    = (__bf16*)(ws + 80216064);                    // 37,748,736
  __bf16* kbuf  = (__bf16*)(ws + 117964800);                   // 37,748,736
  __bf16* vbuf  = (__bf16*)(ws + 155713536);                   // 37,748,736
  __bf16* ao    = hsb;  // reuse: hs_bf16 dead after gemm_qkv

  pack_w_kernel<<<dim3(36, 36, 4), 256, 0, stream>>>(wq, wk, wv, wo, wqkvT, woT);
  pack_hs_kernel<<<18432, 256, 0, stream>>>((const float4*)hs, (bf16x4*)hsb);
  gemm8p_kernel<0><<<864, 512, 0, stream>>>(hsb, wqkvT, bq, bk, bv, qb, kbuf, vbuf, nullptr);
  attn_kernel<<<3072, 256, 0, stream>>>(qb, kbuf, vbuf, ao);
  gemm8p_kernel<1><<<576, 512, 0, stream>>>(ao, woT, bo, nullptr, nullptr, nullptr, nullptr, nullptr, out);
}

// Round 6
// 767.690 us; speedup vs baseline: 2.0292x; 2.0292x over previous
//
#include <hip/hip_runtime.h>
#include <hip/hip_bf16.h>

typedef __attribute__((ext_vector_type(8))) __bf16 bf16x8;
typedef __attribute__((ext_vector_type(4))) __bf16 bf16x4;
typedef __attribute__((ext_vector_type(4))) float  f32x4;

#define DIM   2304
#define NH    24
#define HD    96
#define SPS   512

// ---- async global->LDS, 16B per lane (dest = wave-uniform base + lane*16) ----
__device__ __forceinline__ void gload16(const void* gp, void* lp) {
  __builtin_amdgcn_global_load_lds(
      (__attribute__((address_space(1))) void*)(unsigned long long)gp,
      (__attribute__((address_space(3))) void*)lp, 16, 0, 0);
}

// ---- weight transpose + bf16 cast: dst[n][k] = (bf16) src[k][n] ----
__global__ __launch_bounds__(256) void pack_w_kernel(
    const float* __restrict__ wq, const float* __restrict__ wk,
    const float* __restrict__ wv, const float* __restrict__ wo,
    __bf16* __restrict__ dqkv, __bf16* __restrict__ dwo)
{
  __shared__ float t[64][65];
  const int z = blockIdx.z;
  const float* src = (z == 0) ? wq : (z == 1) ? wk : (z == 2) ? wv : wo;
  __bf16* dst = (z < 3) ? (dqkv + (size_t)z * DIM * DIM) : dwo;
  const int n0 = blockIdx.x * 64, k0 = blockIdx.y * 64;
  const int tx = threadIdx.x & 63, ty = threadIdx.x >> 6;
#pragma unroll
  for (int j = 0; j < 64; j += 4)
    t[ty + j][tx] = src[(size_t)(k0 + ty + j) * DIM + n0 + tx];
  __syncthreads();
#pragma unroll
  for (int j = 0; j < 64; j += 4)
    dst[(size_t)(n0 + ty + j) * DIM + k0 + tx] = (__bf16)t[tx][ty + j];
}

// ---- hidden_states fp32 -> bf16 ----
__global__ __launch_bounds__(256) void pack_hs_kernel(
    const float4* __restrict__ src, bf16x4* __restrict__ dst)
{
  const int i = blockIdx.x * 256 + threadIdx.x;
  const float4 f = src[i];
  bf16x4 o = { (__bf16)f.x, (__bf16)f.y, (__bf16)f.z, (__bf16)f.w };
  dst[i] = o;
}

// ================= 8-phase GEMM, counted-vmcnt pipeline (r4 schedule) =================
// A [M][K], B [N][K] row-major bf16. 512 thr = 8 waves (2M x 4N), BK=64,
// XOR-swizzled LDS both-sides. EPI0: 256x256 tile (MF=4), QKV scatter+RoPE,
// V written TRANSPOSED [b'][h][d][key]. EPI1: 128x256 tile (MF=2), fp32 C.
// NOTE: no extra fragment ping/pong — 512-thr block => >=2 waves/SIMD => 256
// regs/wave cap; acc(128 AGPR)+frags+addr saturates it (r5 spilled: 4.4GB scratch).

template<int NJ>
__device__ __forceinline__ void stage_half(
    const __bf16* __restrict__ X, __bf16* lX, int r0, int k0,
    int srow, int schunk, int dslot)
{
#pragma unroll
  for (int j = 0; j < NJ; ++j)
    gload16(X + (size_t)(r0 + j * 64 + srow) * DIM + k0 + schunk,
            lX + (j * 64 + srow) * 64 + dslot);
}

template<int MF, int H, int Q, bool LA, bool LB>
__device__ __forceinline__ void phase8(
    const char* ab, const char* bb, int wm, int wn, int laneA0, int laneA1,
    bf16x8 (&a)[MF][2], bf16x8 (&bq)[2][2][2], f32x4 (&acc)[2 * MF][4])
{
  if (LA) {
#pragma unroll
    for (int fm = 0; fm < MF; ++fm) {
      a[fm][0] = *(const bf16x8*)(ab + (wm * (MF * 32) + H * (MF * 16) + fm * 16) * 128 + laneA0);
      a[fm][1] = *(const bf16x8*)(ab + (wm * (MF * 32) + H * (MF * 16) + fm * 16) * 128 + laneA1);
    }
  }
  if (LB) {
#pragma unroll
    for (int fn = 0; fn < 2; ++fn) {
      bq[Q][fn][0] = *(const bf16x8*)(bb + (wn * 64 + Q * 32 + fn * 16) * 128 + laneA0);
      bq[Q][fn][1] = *(const bf16x8*)(bb + (wn * 64 + Q * 32 + fn * 16) * 128 + laneA1);
    }
  }
  __builtin_amdgcn_s_barrier();
  asm volatile("s_waitcnt lgkmcnt(0)" ::: "memory");
  __builtin_amdgcn_s_setprio(1);
#pragma unroll
  for (int fm = 0; fm < MF; ++fm)
#pragma unroll
    for (int fn = 0; fn < 2; ++fn)
#pragma unroll
      for (int kk = 0; kk < 2; ++kk)
        acc[H * MF + fm][Q * 2 + fn] = __builtin_amdgcn_mfma_f32_16x16x32_bf16(
            a[fm][kk], bq[Q][fn][kk], acc[H * MF + fm][Q * 2 + fn], 0, 0, 0);
  __builtin_amdgcn_s_setprio(0);
  __builtin_amdgcn_s_barrier();
}

template<int EPI>
__global__ __launch_bounds__(512, 2) void gemm8p_kernel(
    const __bf16* __restrict__ A, const __bf16* __restrict__ B,
    const float* __restrict__ b0, const float* __restrict__ b1, const float* __restrict__ b2,
    __bf16* __restrict__ o0, __bf16* __restrict__ o1, __bf16* __restrict__ o2,
    float* __restrict__ fout)
{
  constexpr int MF = (EPI == 0) ? 4 : 2;         // A fragments per phase-half
  constexpr int MROWS = MF * 64;                 // 256 or 128
  __shared__ __align__(16) __bf16 As[2][MROWS * 64];
  __shared__ __align__(16) __bf16 Bs[2][256 * 64];
  __shared__ float tcos[640], tsin[640];
  const int tid = threadIdx.x;
  if (EPI == 0) {
    for (int i = tid; i < 640; i += 512) {
      int pos, jj = i & 15;
      if (i < 128)      pos = i >> 4;
      else if (i < 384) pos = (i - 128) >> 4;
      else              pos = (i - 384) >> 4;
      const float invf = exp2f(-(float)jj * 0.83048202372184059f); // 10000^(-jj/16)
      float s, c;
      sincosf((float)pos * invf, &s, &c);
      tcos[i] = c; tsin[i] = s;
    }
  }
  const int wid = tid >> 6, l = tid & 63;
  const int lq = l & 15, lg = l >> 4;
  const int wm = wid >> 2, wn = wid & 3;
  const int bid = blockIdx.x;
  const int xcd = bid & 7, local = bid >> 3;
  int m0, n0;
  if (EPI == 0) {                                 // 864 blocks: 32 m x 27 n
    m0 = (xcd * 4 + (local & 3)) * 256;
    n0 = (local >> 2) * 256;
  } else {                                        // 576 blocks: 64 m x 9 n
    m0 = (xcd * 8 + (local & 7)) * 128;
    n0 = (local >> 3) * 256;
  }
  const int srow = tid >> 3;
  const int schunk = ((tid & 7) ^ (srow & 7)) * 8;
  const int dslot = (tid & 7) * 8;
  const int laneA0 = lq * 128 + ((lg * 16) ^ ((lq & 7) << 4));
  const int laneA1 = lq * 128 + ((64 + lg * 16) ^ ((lq & 7) << 4));

  f32x4 acc[2 * MF][4] = {};
  bf16x8 a[MF][2], bq[2][2][2];

  // prologue: stage tiles 0,1 (MF+4 loads each)
  stage_half<MF>(A, As[0], m0, 0, srow, schunk, dslot);
  stage_half<4>(B, Bs[0], n0, 0, srow, schunk, dslot);
  stage_half<MF>(A, As[1], m0, 64, srow, schunk, dslot);
  stage_half<4>(B, Bs[1], n0, 64, srow, schunk, dslot);
  if (EPI == 0) asm volatile("s_waitcnt vmcnt(8)" ::: "memory");
  else          asm volatile("s_waitcnt vmcnt(6)" ::: "memory");
  __builtin_amdgcn_s_barrier();

  const char* a0p = (const char*)&As[0][0];
  const char* b0p = (const char*)&Bs[0][0];
  const char* a1p = (const char*)&As[1][0];
  const char* b1p = (const char*)&Bs[1][0];

#define TILE_STAGED(AP, BP, SA, SB, KN)                                          \
  phase8<MF, 0, 0, true,  true >(AP, BP, wm, wn, laneA0, laneA1, a, bq, acc);    \
  phase8<MF, 0, 1, false, true >(AP, BP, wm, wn, laneA0, laneA1, a, bq, acc);    \
  stage_half<4>(B, SB, n0, KN, srow, schunk, dslot);                             \
  phase8<MF, 1, 1, true,  false>(AP, BP, wm, wn, laneA0, laneA1, a, bq, acc);    \
  stage_half<MF>(A, SA, m0, KN, srow, schunk, dslot);                            \
  phase8<MF, 1, 0, false, false>(AP, BP, wm, wn, laneA0, laneA1, a, bq, acc);    \
  if (EPI == 0) asm volatile("s_waitcnt vmcnt(8)" ::: "memory");                 \
  else          asm volatile("s_waitcnt vmcnt(6)" ::: "memory");                 \
  __builtin_amdgcn_s_barrier();

#define TILE_PLAIN(AP, BP)                                                       \
  phase8<MF, 0, 0, true,  true >(AP, BP, wm, wn, laneA0, laneA1, a, bq, acc);    \
  phase8<MF, 0, 1, false, true >(AP, BP, wm, wn, laneA0, laneA1, a, bq, acc);    \
  phase8<MF, 1, 1, true,  false>(AP, BP, wm, wn, laneA0, laneA1, a, bq, acc);    \
  phase8<MF, 1, 0, false, false>(AP, BP, wm, wn, laneA0, laneA1, a, bq, acc);

  for (int tt = 0; tt < 34; tt += 2) {
    TILE_STAGED(a0p, b0p, As[0], Bs[0], (tt + 2) * 64)
    TILE_STAGED(a1p, b1p, As[1], Bs[1], (tt + 3) * 64)
  }
  TILE_PLAIN(a0p, b0p)
  asm volatile("s_waitcnt vmcnt(0)" ::: "memory");
  __builtin_amdgcn_s_barrier();
  TILE_PLAIN(a1p, b1p)
#undef TILE_STAGED
#undef TILE_PLAIN

  if (EPI == 0) {
    const int mat = n0 / DIM;
    const int nb = n0 - mat * DIM;
    const float* bias = (mat == 0) ? b0 : (mat == 1) ? b1 : b2;
    __bf16* outp = (mat == 0) ? o0 : (mat == 1) ? o1 : o2;
#pragma unroll
    for (int mr = 0; mr < 8; ++mr) {
      const int gq = (m0 + wm * 128 + mr * 16) >> 4;
      const int si = gq * 4 + lg;
      const int pos3[3] = { si >> 8, (si >> 4) & 15, si & 15 };
#pragma unroll
      for (int p = 0; p < 2; ++p) {
        const int nlo = nb + wn * 64 + (2 * p) * 16 + lq;
        const int nhi = nlo + 16;
        const int hlo = nlo / HD, dlo = nlo - hlo * HD;
        const int hhi = nhi / HD, dhi = nhi - hhi * HD;
        const float blo = bias[nlo], bhi = bias[nhi];
        float c = 1.f, s = 0.f;
        if (mat < 2) {
          const int cix = dlo >> 5;
          const int toff = ((cix == 0) ? 0 : (cix == 1) ? 128 : 384) + pos3[cix] * 16 + lq;
          c = tcos[toff]; s = tsin[toff];
        }
#pragma unroll
        for (int r = 0; r < 4; ++r) {
          const int bp = lg * 4 + r;
          const float x1 = acc[mr][2 * p][r] + blo;
          const float x2 = acc[mr][2 * p + 1][r] + bhi;
          float y1 = x1, y2 = x2;
          if (mat < 2) { y1 = x1 * c - x2 * s; y2 = x2 * c + x1 * s; }
          if (mat == 2) {
            // V stored TRANSPOSED: [b'][h][d][key] so attn reads coalesced V^T rows
            outp[((size_t)(bp * NH + hlo) * HD + dlo) * SPS + gq] = (__bf16)y1;
            outp[((size_t)(bp * NH + hhi) * HD + dhi) * SPS + gq] = (__bf16)y2;
          } else {
            outp[((size_t)(bp * NH + hlo) * SPS + gq) * HD + dlo] = (__bf16)y1;
            outp[((size_t)(bp * NH + hhi) * SPS + gq) * HD + dhi] = (__bf16)y2;
          }
        }
      }
    }
  } else {
#pragma unroll
    for (int mr = 0; mr < 4; ++mr) {
      const int rbase = m0 + wm * 64 + mr * 16;
#pragma unroll
      for (int nr = 0; nr < 4; ++nr) {
        const int n = n0 + wn * 64 + nr * 16 + lq;
        const float bia = b0[n];
#pragma unroll
        for (int r = 0; r < 4; ++r)
          fout[(size_t)(rbase + lg * 4 + r) * DIM + n] = acc[mr][nr][r] + bia;
      }
    }
  }
}

// ---- flash attention, barrier-free: 4 independent waves x 16 q-rows.
//      K read as rows from global; V^T fragments read directly from global
//      (vT layout [b'][h][d][key], L2-resident after XCD-chunked swizzle).
//      Pl is wave-private LDS (no cross-wave sync anywhere). ----
__global__ __launch_bounds__(256) void attn_kernel(
    const __bf16* __restrict__ q, const __bf16* __restrict__ k,
    const __bf16* __restrict__ vT, __bf16* __restrict__ ao)
{
  __shared__ __bf16 Pl[4][16 * 72];     // per-wave P [q][key], padded rows
  const int tid = threadIdx.x;
  const int w = tid >> 6, l = tid & 63;
  const int lq = l & 15, lg = l >> 4;
  // bijective chunked XCD swizzle over 3072 blocks (384 per XCD), qt innermost
  const int bid = blockIdx.x;
  const int swz = (bid & 7) * 384 + (bid >> 3);
  const int qt = swz & 7;
  const int h  = (swz >> 3) % NH;
  const int bp = swz / (NH * 8);
  const size_t bh = (size_t)bp * NH + h;
  const __bf16* qb = q + bh * SPS * HD;
  const __bf16* kb = k + bh * SPS * HD;
  const __bf16* vb = vT + bh * HD * SPS;   // [d][key]
  bf16x8 qf[3];
  {
    const __bf16* qr = qb + (size_t)(qt * 64 + w * 16 + lq) * HD + lg * 8;
    qf[0] = *(const bf16x8*)(qr);
    qf[1] = *(const bf16x8*)(qr + 32);
    qf[2] = *(const bf16x8*)(qr + 64);
  }
  const float sc = 0.10206207261596575f * 1.4426950408889634f; // 96^-0.5 * log2(e)
  float m_run = -1e30f, l_run = 0.f;
  f32x4 o[6] = {};
  for (int kb0 = 0; kb0 < SPS; kb0 += 64) {
    // S^T = K * Q^T (rows=key, cols=q) -> lane owns col q = lq
    f32x4 st[4];
    __builtin_amdgcn_s_setprio(1);
#pragma unroll
    for (int t2 = 0; t2 < 4; ++t2) {
      const __bf16* kr = kb + (size_t)(kb0 + t2 * 16 + lq) * HD + lg * 8;
      bf16x8 k0f = *(const bf16x8*)(kr);
      bf16x8 k1f = *(const bf16x8*)(kr + 32);
      bf16x8 k2f = *(const bf16x8*)(kr + 64);
      f32x4 s = {};
      s = __builtin_amdgcn_mfma_f32_16x16x32_bf16(k0f, qf[0], s, 0, 0, 0);
      s = __builtin_amdgcn_mfma_f32_16x16x32_bf16(k1f, qf[1], s, 0, 0, 0);
      s = __builtin_amdgcn_mfma_f32_16x16x32_bf16(k2f, qf[2], s, 0, 0, 0);
      st[t2] = s;
    }
    __builtin_amdgcn_s_setprio(0);
    float tmax = -1e30f;
#pragma unroll
    for (int t2 = 0; t2 < 4; ++t2)
#pragma unroll
      for (int r = 0; r < 4; ++r) tmax = fmaxf(tmax, st[t2][r]);
    tmax = fmaxf(tmax, __shfl_xor(tmax, 16));
    tmax = fmaxf(tmax, __shfl_xor(tmax, 32));
    tmax *= sc;
    const float m_new = fmaxf(m_run, tmax);
    const float alpha = exp2f(m_run - m_new);
    float tsum = 0.f;
#pragma unroll
    for (int t2 = 0; t2 < 4; ++t2) {
      bf16x4 pb;
#pragma unroll
      for (int r = 0; r < 4; ++r) {
        const float p = exp2f(st[t2][r] * sc - m_new);
        tsum += p;
        pb[r] = (__bf16)p;
      }
      *(bf16x4*)&Pl[w][lq * 72 + t2 * 16 + lg * 4] = pb;  // wave-private, no barrier
    }
    tsum += __shfl_xor(tsum, 16);
    tsum += __shfl_xor(tsum, 32);
    l_run = l_run * alpha + tsum;
    m_run = m_new;
    float al[4];
#pragma unroll
    for (int r = 0; r < 4; ++r) al[r] = __shfl(alpha, lg * 4 + r);
#pragma unroll
    for (int ni = 0; ni < 6; ++ni)
#pragma unroll
      for (int r = 0; r < 4; ++r) o[ni][r] *= al[r];
    // O += P * V : B-fragments straight from global V^T rows (L2-hit)
#pragma unroll
    for (int ks = 0; ks < 2; ++ks) {
      bf16x8 pa = *(const bf16x8*)&Pl[w][lq * 72 + ks * 32 + lg * 8];
      __builtin_amdgcn_s_setprio(1);
#pragma unroll
      for (int ni = 0; ni < 6; ++ni) {
        bf16x8 vf = *(const bf16x8*)(vb + (size_t)(ni * 16 + lq) * SPS + kb0 + ks * 32 + lg * 8);
        o[ni] = __builtin_amdgcn_mfma_f32_16x16x32_bf16(pa, vf, o[ni], 0, 0, 0);
      }
      __builtin_amdgcn_s_setprio(0);
    }
  }
  float linv[4];
#pragma unroll
  for (int r = 0; r < 4; ++r) linv[r] = 1.f / __shfl(l_run, lg * 4 + r);
#pragma unroll
  for (int ni = 0; ni < 6; ++ni)
#pragma unroll
    for (int r = 0; r < 4; ++r) {
      const int gq = qt * 64 + w * 16 + lg * 4 + r;
      const int d = ni * 16 + lq;
      ao[(size_t)(gq * 16 + bp) * DIM + h * HD + d] = (__bf16)(o[ni][r] * linv[r]);
    }
}

extern "C" void kernel_launch(void* const* d_in, const int* in_sizes, int n_in,
                              void* d_out, int out_size, void* d_ws, size_t ws_size,
                              hipStream_t stream) {
  const float* hs = (const float*)d_in[0];
  const float* wq = (const float*)d_in[1];
  const float* bq = (const float*)d_in[2];
  const float* wk = (const float*)d_in[3];
  const float* bk = (const float*)d_in[4];
  const float* wv = (const float*)d_in[5];
  const float* bv = (const float*)d_in[6];
  const float* wo = (const float*)d_in[7];
  const float* bo = (const float*)d_in[8];
  float* out = (float*)d_out;

  char* ws = (char*)d_ws;
  __bf16* wqkvT = (__bf16*)(ws);                               // 31,850,496
  __bf16* woT   = (__bf16*)(ws + 31850496);                    // 10,616,832
  __bf16* hsb   = (__bf16*)(ws + 42467328);                    // 37,748,736
  __bf16* qb    = (__bf16*)(ws + 80216064);                    // 37,748,736
  __bf16* kbuf  = (__bf16*)(ws + 117964800);                   // 37,748,736
  __bf16* vbufT = (__bf16*)(ws + 155713536);                   // 37,748,736 (V^T layout)
  __bf16* ao    = hsb;  // reuse: hs_bf16 dead after gemm_qkv

  pack_w_kernel<<<dim3(36, 36, 4), 256, 0, stream>>>(wq, wk, wv, wo, wqkvT, woT);
  pack_hs_kernel<<<18432, 256, 0, stream>>>((const float4*)hs, (bf16x4*)hsb);
  gemm8p_kernel<0><<<864, 512, 0, stream>>>(hsb, wqkvT, bq, bk, bv, qb, kbuf, vbufT, nullptr);
  attn_kernel<<<3072, 256, 0, stream>>>(qb, kbuf, vbufT, ao);
  gemm8p_kernel<1><<<576, 512, 0, stream>>>(ao, woT, bo, nullptr, nullptr, nullptr, nullptr, nullptr, out);
}

// Round 7
// 631.841 us; speedup vs baseline: 2.4655x; 1.2150x over previous
//
#include <hip/hip_runtime.h>
#include <hip/hip_bf16.h>

typedef __attribute__((ext_vector_type(8))) __bf16 bf16x8;
typedef __attribute__((ext_vector_type(4))) __bf16 bf16x4;
typedef __attribute__((ext_vector_type(4))) float  f32x4;

#define DIM   2304
#define NH    24
#define HD    96
#define SPS   512

// ---- async global->LDS, 16B per lane (dest = wave-uniform base + lane*16) ----
__device__ __forceinline__ void gload16(const void* gp, void* lp) {
  __builtin_amdgcn_global_load_lds(
      (__attribute__((address_space(1))) void*)(unsigned long long)gp,
      (__attribute__((address_space(3))) void*)lp, 16, 0, 0);
}

// ---- fused prep: weight transpose/cast (blocks 0..5183) + hs cast (rest) ----
__global__ __launch_bounds__(256) void prep_kernel(
    const float* __restrict__ hs,
    const float* __restrict__ wq, const float* __restrict__ wk,
    const float* __restrict__ wv, const float* __restrict__ wo,
    __bf16* __restrict__ hsb, __bf16* __restrict__ wqkvT, __bf16* __restrict__ woT)
{
  __shared__ float t[64][65];
  const int bid = blockIdx.x;
  const int tid = threadIdx.x;
  if (bid < 5184) {
    const int z = bid / 1296;
    const int rest = bid - z * 1296;
    const int n0 = (rest % 36) * 64, k0 = (rest / 36) * 64;
    const float* src = (z == 0) ? wq : (z == 1) ? wk : (z == 2) ? wv : wo;
    __bf16* dst = (z < 3) ? (wqkvT + (size_t)z * DIM * DIM) : woT;
    const int tx = tid & 63, ty = tid >> 6;
#pragma unroll
    for (int j = 0; j < 64; j += 4)
      t[ty + j][tx] = src[(size_t)(k0 + ty + j) * DIM + n0 + tx];
    __syncthreads();
#pragma unroll
    for (int j = 0; j < 64; j += 4)
      dst[(size_t)(n0 + ty + j) * DIM + k0 + tx] = (__bf16)t[tx][ty + j];
  } else {
    const int i = (bid - 5184) * 256 + tid;
    const float4 f = ((const float4*)hs)[i];
    bf16x4 o = { (__bf16)f.x, (__bf16)f.y, (__bf16)f.z, (__bf16)f.w };
    ((bf16x4*)hsb)[i] = o;
  }
}

// ================= 8-phase GEMM, counted-vmcnt pipeline (r4 schedule) =================
template<int NJ>
__device__ __forceinline__ void stage_half(
    const __bf16* __restrict__ X, __bf16* lX, int r0, int k0,
    int srow, int schunk, int dslot)
{
#pragma unroll
  for (int j = 0; j < NJ; ++j)
    gload16(X + (size_t)(r0 + j * 64 + srow) * DIM + k0 + schunk,
            lX + (j * 64 + srow) * 64 + dslot);
}

template<int MF, int H, int Q, bool LA, bool LB>
__device__ __forceinline__ void phase8(
    const char* ab, const char* bb, int wm, int wn, int laneA0, int laneA1,
    bf16x8 (&a)[MF][2], bf16x8 (&bq)[2][2][2], f32x4 (&acc)[2 * MF][4])
{
  if (LA) {
#pragma unroll
    for (int fm = 0; fm < MF; ++fm) {
      a[fm][0] = *(const bf16x8*)(ab + (wm * (MF * 32) + H * (MF * 16) + fm * 16) * 128 + laneA0);
      a[fm][1] = *(const bf16x8*)(ab + (wm * (MF * 32) + H * (MF * 16) + fm * 16) * 128 + laneA1);
    }
  }
  if (LB) {
#pragma unroll
    for (int fn = 0; fn < 2; ++fn) {
      bq[Q][fn][0] = *(const bf16x8*)(bb + (wn * 64 + Q * 32 + fn * 16) * 128 + laneA0);
      bq[Q][fn][1] = *(const bf16x8*)(bb + (wn * 64 + Q * 32 + fn * 16) * 128 + laneA1);
    }
  }
  __builtin_amdgcn_s_barrier();
  asm volatile("s_waitcnt lgkmcnt(0)" ::: "memory");
  __builtin_amdgcn_s_setprio(1);
#pragma unroll
  for (int fm = 0; fm < MF; ++fm)
#pragma unroll
    for (int fn = 0; fn < 2; ++fn)
#pragma unroll
      for (int kk = 0; kk < 2; ++kk)
        acc[H * MF + fm][Q * 2 + fn] = __builtin_amdgcn_mfma_f32_16x16x32_bf16(
            a[fm][kk], bq[Q][fn][kk], acc[H * MF + fm][Q * 2 + fn], 0, 0, 0);
  __builtin_amdgcn_s_setprio(0);
  __builtin_amdgcn_s_barrier();
}

template<int EPI>
__global__ __launch_bounds__(512, 2) void gemm8p_kernel(
    const __bf16* __restrict__ A, const __bf16* __restrict__ B,
    const float* __restrict__ b0, const float* __restrict__ b1, const float* __restrict__ b2,
    __bf16* __restrict__ o0, __bf16* __restrict__ o1, __bf16* __restrict__ o2,
    float* __restrict__ fout)
{
  constexpr int MF = (EPI == 0) ? 4 : 2;
  constexpr int MROWS = MF * 64;
  __shared__ __align__(16) __bf16 As[2][MROWS * 64];
  __shared__ __align__(16) __bf16 Bs[2][256 * 64];
  __shared__ float tcos[640], tsin[640];
  const int tid = threadIdx.x;
  if (EPI == 0) {
    for (int i = tid; i < 640; i += 512) {
      int pos, jj = i & 15;
      if (i < 128)      pos = i >> 4;
      else if (i < 384) pos = (i - 128) >> 4;
      else              pos = (i - 384) >> 4;
      const float invf = exp2f(-(float)jj * 0.83048202372184059f); // 10000^(-jj/16)
      float s, c;
      sincosf((float)pos * invf, &s, &c);
      tcos[i] = c; tsin[i] = s;
    }
  }
  const int wid = tid >> 6, l = tid & 63;
  const int lq = l & 15, lg = l >> 4;
  const int wm = wid >> 2, wn = wid & 3;
  const int bid = blockIdx.x;
  const int xcd = bid & 7, local = bid >> 3;
  int m0, n0;
  if (EPI == 0) {                                 // 864 blocks: 32 m x 27 n
    m0 = (xcd * 4 + (local & 3)) * 256;
    n0 = (local >> 2) * 256;
  } else {                                        // 576 blocks: 64 m x 9 n
    m0 = (xcd * 8 + (local & 7)) * 128;
    n0 = (local >> 3) * 256;
  }
  const int srow = tid >> 3;
  const int schunk = ((tid & 7) ^ (srow & 7)) * 8;
  const int dslot = (tid & 7) * 8;
  const int laneA0 = lq * 128 + ((lg * 16) ^ ((lq & 7) << 4));
  const int laneA1 = lq * 128 + ((64 + lg * 16) ^ ((lq & 7) << 4));

  f32x4 acc[2 * MF][4] = {};
  bf16x8 a[MF][2], bq[2][2][2];

  stage_half<MF>(A, As[0], m0, 0, srow, schunk, dslot);
  stage_half<4>(B, Bs[0], n0, 0, srow, schunk, dslot);
  stage_half<MF>(A, As[1], m0, 64, srow, schunk, dslot);
  stage_half<4>(B, Bs[1], n0, 64, srow, schunk, dslot);
  if (EPI == 0) asm volatile("s_waitcnt vmcnt(8)" ::: "memory");
  else          asm volatile("s_waitcnt vmcnt(6)" ::: "memory");
  __builtin_amdgcn_s_barrier();

  const char* a0p = (const char*)&As[0][0];
  const char* b0p = (const char*)&Bs[0][0];
  const char* a1p = (const char*)&As[1][0];
  const char* b1p = (const char*)&Bs[1][0];

#define TILE_STAGED(AP, BP, SA, SB, KN)                                          \
  phase8<MF, 0, 0, true,  true >(AP, BP, wm, wn, laneA0, laneA1, a, bq, acc);    \
  phase8<MF, 0, 1, false, true >(AP, BP, wm, wn, laneA0, laneA1, a, bq, acc);    \
  stage_half<4>(B, SB, n0, KN, srow, schunk, dslot);                             \
  phase8<MF, 1, 1, true,  false>(AP, BP, wm, wn, laneA0, laneA1, a, bq, acc);    \
  stage_half<MF>(A, SA, m0, KN, srow, schunk, dslot);                            \
  phase8<MF, 1, 0, false, false>(AP, BP, wm, wn, laneA0, laneA1, a, bq, acc);    \
  if (EPI == 0) asm volatile("s_waitcnt vmcnt(8)" ::: "memory");                 \
  else          asm volatile("s_waitcnt vmcnt(6)" ::: "memory");                 \
  __builtin_amdgcn_s_barrier();

#define TILE_PLAIN(AP, BP)                                                       \
  phase8<MF, 0, 0, true,  true >(AP, BP, wm, wn, laneA0, laneA1, a, bq, acc);    \
  phase8<MF, 0, 1, false, true >(AP, BP, wm, wn, laneA0, laneA1, a, bq, acc);    \
  phase8<MF, 1, 1, true,  false>(AP, BP, wm, wn, laneA0, laneA1, a, bq, acc);    \
  phase8<MF, 1, 0, false, false>(AP, BP, wm, wn, laneA0, laneA1, a, bq, acc);

  for (int tt = 0; tt < 34; tt += 2) {
    TILE_STAGED(a0p, b0p, As[0], Bs[0], (tt + 2) * 64)
    TILE_STAGED(a1p, b1p, As[1], Bs[1], (tt + 3) * 64)
  }
  TILE_PLAIN(a0p, b0p)
  asm volatile("s_waitcnt vmcnt(0)" ::: "memory");
  __builtin_amdgcn_s_barrier();
  TILE_PLAIN(a1p, b1p)
#undef TILE_STAGED
#undef TILE_PLAIN

  if (EPI == 0) {
    const int mat = n0 / DIM;
    const int nb = n0 - mat * DIM;
    const float* bias = (mat == 0) ? b0 : (mat == 1) ? b1 : b2;
    __bf16* outp = (mat == 0) ? o0 : (mat == 1) ? o1 : o2;
#pragma unroll
    for (int mr = 0; mr < 8; ++mr) {
      const int gq = (m0 + wm * 128 + mr * 16) >> 4;
      const int si = gq * 4 + lg;
      const int pos3[3] = { si >> 8, (si >> 4) & 15, si & 15 };
#pragma unroll
      for (int p = 0; p < 2; ++p) {
        const int nlo = nb + wn * 64 + (2 * p) * 16 + lq;
        const int nhi = nlo + 16;
        const int hlo = nlo / HD, dlo = nlo - hlo * HD;
        const int hhi = nhi / HD, dhi = nhi - hhi * HD;
        const float blo = bias[nlo], bhi = bias[nhi];
        float c = 1.f, s = 0.f;
        if (mat < 2) {
          const int cix = dlo >> 5;
          const int toff = ((cix == 0) ? 0 : (cix == 1) ? 128 : 384) + pos3[cix] * 16 + lq;
          c = tcos[toff]; s = tsin[toff];
        }
#pragma unroll
        for (int r = 0; r < 4; ++r) {
          const int bp = lg * 4 + r;
          const float x1 = acc[mr][2 * p][r] + blo;
          const float x2 = acc[mr][2 * p + 1][r] + bhi;
          float y1 = x1, y2 = x2;
          if (mat < 2) { y1 = x1 * c - x2 * s; y2 = x2 * c + x1 * s; }
          outp[((size_t)(bp * NH + hlo) * SPS + gq) * HD + dlo] = (__bf16)y1;
          outp[((size_t)(bp * NH + hhi) * SPS + gq) * HD + dhi] = (__bf16)y2;
        }
      }
    }
  } else {
#pragma unroll
    for (int mr = 0; mr < 4; ++mr) {
      const int rbase = m0 + wm * 64 + mr * 16;
#pragma unroll
      for (int nr = 0; nr < 4; ++nr) {
        const int n = n0 + wn * 64 + nr * 16 + lq;
        const float bia = b0[n];
#pragma unroll
        for (int r = 0; r < 4; ++r)
          fout[(size_t)(rbase + lg * 4 + r) * DIM + n] = acc[mr][nr][r] + bia;
      }
    }
  }
}

// ---- V transpose: [b'h][g][d] -> [b'h][d][g], LDS-tiled, XOR-swizzled ----
__global__ __launch_bounds__(256) void transpose_v_kernel(
    const __bf16* __restrict__ v, __bf16* __restrict__ vT)
{
  __shared__ __bf16 t[96][72];   // [d][g ^ swz], row stride 144B (16B-aligned)
  const int tid = threadIdx.x, bid = blockIdx.x;
  const int bh = bid >> 3, g0 = (bid & 7) * 64;
  const __bf16* src = v + ((size_t)bh * SPS + g0) * HD;
#pragma unroll
  for (int it = 0; it < 3; ++it) {
    const int lin = it * 256 + tid;
    const int row = lin / 12, c8 = (lin % 12) * 8;
    bf16x8 x = *(const bf16x8*)(src + row * HD + c8);
#pragma unroll
    for (int j = 0; j < 8; ++j) {
      const int d = c8 + j;
      t[d][row ^ ((d & 7) << 3)] = x[j];
    }
  }
  __syncthreads();
  __bf16* dst = vT + (size_t)bh * HD * SPS + g0;
#pragma unroll
  for (int it = 0; it < 3; ++it) {
    const int lin = it * 256 + tid;
    const int d = lin / 8, gc = (lin % 8) * 8;
    bf16x8 o = *(const bf16x8*)&t[d][gc ^ ((d & 7) << 3)];
    *(bf16x8*)(dst + (size_t)d * SPS + gc) = o;
  }
}

// ---- flash attention, barrier-free, KVBLK=128, defer-max (THR=8).
//      4 independent waves x 16 q-rows; K rows + V^T rows read from global
//      (L2-resident via XCD-chunked swizzle); P in wave-private LDS. ----
__global__ __launch_bounds__(256) void attn_kernel(
    const __bf16* __restrict__ q, const __bf16* __restrict__ k,
    const __bf16* __restrict__ vT, __bf16* __restrict__ ao)
{
  __shared__ __bf16 Pl[4][16 * 136];    // per-wave P [q][key], stride 272B
  const int tid = threadIdx.x;
  const int w = tid >> 6, l = tid & 63;
  const int lq = l & 15, lg = l >> 4;
  const int bid = blockIdx.x;
  const int swz = (bid & 7) * 384 + (bid >> 3);
  const int qt = swz & 7;
  const int h  = (swz >> 3) % NH;
  const int bp = swz / (NH * 8);
  const size_t bh = (size_t)bp * NH + h;
  const __bf16* qb = q + bh * SPS * HD;
  const __bf16* kb = k + bh * SPS * HD;
  const __bf16* vb = vT + bh * HD * SPS;   // [d][key]
  bf16x8 qf[3];
  {
    const __bf16* qr = qb + (size_t)(qt * 64 + w * 16 + lq) * HD + lg * 8;
    qf[0] = *(const bf16x8*)(qr);
    qf[1] = *(const bf16x8*)(qr + 32);
    qf[2] = *(const bf16x8*)(qr + 64);
  }
  const float sc = 0.10206207261596575f * 1.4426950408889634f; // 96^-0.5 * log2(e)
  float m_run = -1e30f, l_run = 0.f;     // l_run: per-lane PARTIAL sum for q=lq
  f32x4 o[6] = {};
  for (int kb0 = 0; kb0 < SPS; kb0 += 128) {
    f32x4 st[8];
    __builtin_amdgcn_s_setprio(1);
#pragma unroll
    for (int t2 = 0; t2 < 8; ++t2) {
      const __bf16* kr = kb + (size_t)(kb0 + t2 * 16 + lq) * HD + lg * 8;
      bf16x8 k0f = *(const bf16x8*)(kr);
      bf16x8 k1f = *(const bf16x8*)(kr + 32);
      bf16x8 k2f = *(const bf16x8*)(kr + 64);
      f32x4 s = {};
      s = __builtin_amdgcn_mfma_f32_16x16x32_bf16(k0f, qf[0], s, 0, 0, 0);
      s = __builtin_amdgcn_mfma_f32_16x16x32_bf16(k1f, qf[1], s, 0, 0, 0);
      s = __builtin_amdgcn_mfma_f32_16x16x32_bf16(k2f, qf[2], s, 0, 0, 0);
      st[t2] = s;
    }
    __builtin_amdgcn_s_setprio(0);
    float pmax = -1e30f;
#pragma unroll
    for (int t2 = 0; t2 < 8; ++t2)
#pragma unroll
      for (int r = 0; r < 4; ++r) pmax = fmaxf(pmax, st[t2][r]);
    pmax *= sc;
    if (__any(pmax > m_run + 8.f)) {     // rare: ~once per block
      float mn = fmaxf(m_run, pmax);
      mn = fmaxf(mn, __shfl_xor(mn, 16));
      mn = fmaxf(mn, __shfl_xor(mn, 32));
      const float alpha = exp2f(m_run - mn);
      l_run *= alpha;
      float al[4];
#pragma unroll
      for (int r = 0; r < 4; ++r) al[r] = __shfl(alpha, lg * 4 + r);
#pragma unroll
      for (int ni = 0; ni < 6; ++ni)
#pragma unroll
        for (int r = 0; r < 4; ++r) o[ni][r] *= al[r];
      m_run = mn;
    }
#pragma unroll
    for (int t2 = 0; t2 < 8; ++t2) {
      bf16x4 pb;
#pragma unroll
      for (int r = 0; r < 4; ++r) {
        const float p = exp2f(st[t2][r] * sc - m_run);   // bounded by 2^8
        l_run += p;
        pb[r] = (__bf16)p;
      }
      *(bf16x4*)&Pl[w][lq * 136 + t2 * 16 + lg * 4] = pb;  // wave-private
    }
#pragma unroll
    for (int ks = 0; ks < 4; ++ks) {
      bf16x8 pa = *(const bf16x8*)&Pl[w][lq * 136 + ks * 32 + lg * 8];
      __builtin_amdgcn_s_setprio(1);
#pragma unroll
      for (int ni = 0; ni < 6; ++ni) {
        bf16x8 vf = *(const bf16x8*)(vb + (size_t)(ni * 16 + lq) * SPS + kb0 + ks * 32 + lg * 8);
        o[ni] = __builtin_amdgcn_mfma_f32_16x16x32_bf16(pa, vf, o[ni], 0, 0, 0);
      }
      __builtin_amdgcn_s_setprio(0);
    }
  }
  l_run += __shfl_xor(l_run, 16);
  l_run += __shfl_xor(l_run, 32);
  float linv[4];
#pragma unroll
  for (int r = 0; r < 4; ++r) linv[r] = 1.f / __shfl(l_run, lg * 4 + r);
#pragma unroll
  for (int ni = 0; ni < 6; ++ni)
#pragma unroll
    for (int r = 0; r < 4; ++r) {
      const int gq = qt * 64 + w * 16 + lg * 4 + r;
      const int d = ni * 16 + lq;
      ao[(size_t)(gq * 16 + bp) * DIM + h * HD + d] = (__bf16)(o[ni][r] * linv[r]);
    }
}

extern "C" void kernel_launch(void* const* d_in, const int* in_sizes, int n_in,
                              void* d_out, int out_size, void* d_ws, size_t ws_size,
                              hipStream_t stream) {
  const float* hs = (const float*)d_in[0];
  const float* wq = (const float*)d_in[1];
  const float* bq = (const float*)d_in[2];
  const float* wk = (const float*)d_in[3];
  const float* bk = (const float*)d_in[4];
  const float* wv = (const float*)d_in[5];
  const float* bv = (const float*)d_in[6];
  const float* wo = (const float*)d_in[7];
  const float* bo = (const float*)d_in[8];
  float* out = (float*)d_out;

  char* ws = (char*)d_ws;
  // live-range-packed layout, total 193,462,272 bytes (same as before):
  __bf16* wqkvT = (__bf16*)(ws);                  // [0,31.85M)   prep->qkv
  __bf16* hsb   = (__bf16*)(ws + 31850496);       // [31.85,69.6) prep->qkv
  __bf16* qb    = (__bf16*)(ws + 69599232);       // qkv->attn
  __bf16* kbuf  = (__bf16*)(ws + 107347968);      // qkv->attn
  __bf16* vbuf  = (__bf16*)(ws + 145096704);      // qkv->transpose_v
  __bf16* woT   = (__bf16*)(ws + 182845440);      // prep->gemm_out
  __bf16* vbufT = (__bf16*)(ws);                  // transpose_v->attn (over wqkvT+hsb head, both dead)
  __bf16* ao    = vbuf;                           // attn->gemm_out (vbuf dead after transpose_v)

  prep_kernel<<<23616, 256, 0, stream>>>(hs, wq, wk, wv, wo, hsb, wqkvT, woT);
  gemm8p_kernel<0><<<864, 512, 0, stream>>>(hsb, wqkvT, bq, bk, bv, qb, kbuf, vbuf, nullptr);
  transpose_v_kernel<<<3072, 256, 0, stream>>>(vbuf, vbufT);
  attn_kernel<<<3072, 256, 0, stream>>>(qb, kbuf, vbufT, ao);
  gemm8p_kernel<1><<<576, 512, 0, stream>>>(ao, woT, bo, nullptr, nullptr, nullptr, nullptr, nullptr, out);
}

// Round 8
// 523.091 us; speedup vs baseline: 2.9781x; 1.2079x over previous
//
#include <hip/hip_runtime.h>
#include <hip/hip_bf16.h>

typedef __attribute__((ext_vector_type(8))) __bf16 bf16x8;
typedef __attribute__((ext_vector_type(4))) __bf16 bf16x4;
typedef __attribute__((ext_vector_type(4))) float  f32x4;

#define DIM   2304
#define NH    24
#define HD    96
#define SPS   512

// ---- async global->LDS, 16B per lane (dest = wave-uniform base + lane*16) ----
__device__ __forceinline__ void gload16(const void* gp, void* lp) {
  __builtin_amdgcn_global_load_lds(
      (__attribute__((address_space(1))) void*)(unsigned long long)gp,
      (__attribute__((address_space(3))) void*)lp, 16, 0, 0);
}

// ---- fused prep: weight transpose/cast (blocks 0..5183) + hs cast (rest) ----
__global__ __launch_bounds__(256) void prep_kernel(
    const float* __restrict__ hs,
    const float* __restrict__ wq, const float* __restrict__ wk,
    const float* __restrict__ wv, const float* __restrict__ wo,
    __bf16* __restrict__ hsb, __bf16* __restrict__ wqkvT, __bf16* __restrict__ woT)
{
  __shared__ float t[64][65];
  const int bid = blockIdx.x;
  const int tid = threadIdx.x;
  if (bid < 5184) {
    const int z = bid / 1296;
    const int rest = bid - z * 1296;
    const int n0 = (rest % 36) * 64, k0 = (rest / 36) * 64;
    const float* src = (z == 0) ? wq : (z == 1) ? wk : (z == 2) ? wv : wo;
    __bf16* dst = (z < 3) ? (wqkvT + (size_t)z * DIM * DIM) : woT;
    const int tx = tid & 63, ty = tid >> 6;
#pragma unroll
    for (int j = 0; j < 64; j += 4)
      t[ty + j][tx] = src[(size_t)(k0 + ty + j) * DIM + n0 + tx];
    __syncthreads();
#pragma unroll
    for (int j = 0; j < 64; j += 4)
      dst[(size_t)(n0 + ty + j) * DIM + k0 + tx] = (__bf16)t[tx][ty + j];
  } else {
    const int i = (bid - 5184) * 256 + tid;
    const float4 f = ((const float4*)hs)[i];
    bf16x4 o = { (__bf16)f.x, (__bf16)f.y, (__bf16)f.z, (__bf16)f.w };
    ((bf16x4*)hsb)[i] = o;
  }
}

// ================= 8-phase GEMM, counted-vmcnt pipeline (r4 schedule) =================
template<int NJ>
__device__ __forceinline__ void stage_half(
    const __bf16* __restrict__ X, __bf16* lX, int r0, int k0,
    int srow, int schunk, int dslot)
{
#pragma unroll
  for (int j = 0; j < NJ; ++j)
    gload16(X + (size_t)(r0 + j * 64 + srow) * DIM + k0 + schunk,
            lX + (j * 64 + srow) * 64 + dslot);
}

template<int MF, int H, int Q, bool LA, bool LB>
__device__ __forceinline__ void phase8(
    const char* ab, const char* bb, int wm, int wn, int laneA0, int laneA1,
    bf16x8 (&a)[MF][2], bf16x8 (&bq)[2][2][2], f32x4 (&acc)[2 * MF][4])
{
  if (LA) {
#pragma unroll
    for (int fm = 0; fm < MF; ++fm) {
      a[fm][0] = *(const bf16x8*)(ab + (wm * (MF * 32) + H * (MF * 16) + fm * 16) * 128 + laneA0);
      a[fm][1] = *(const bf16x8*)(ab + (wm * (MF * 32) + H * (MF * 16) + fm * 16) * 128 + laneA1);
    }
  }
  if (LB) {
#pragma unroll
    for (int fn = 0; fn < 2; ++fn) {
      bq[Q][fn][0] = *(const bf16x8*)(bb + (wn * 64 + Q * 32 + fn * 16) * 128 + laneA0);
      bq[Q][fn][1] = *(const bf16x8*)(bb + (wn * 64 + Q * 32 + fn * 16) * 128 + laneA1);
    }
  }
  __builtin_amdgcn_s_barrier();
  asm volatile("s_waitcnt lgkmcnt(0)" ::: "memory");
  __builtin_amdgcn_s_setprio(1);
#pragma unroll
  for (int fm = 0; fm < MF; ++fm)
#pragma unroll
    for (int fn = 0; fn < 2; ++fn)
#pragma unroll
      for (int kk = 0; kk < 2; ++kk)
        acc[H * MF + fm][Q * 2 + fn] = __builtin_amdgcn_mfma_f32_16x16x32_bf16(
            a[fm][kk], bq[Q][fn][kk], acc[H * MF + fm][Q * 2 + fn], 0, 0, 0);
  __builtin_amdgcn_s_setprio(0);
  __builtin_amdgcn_s_barrier();
}

template<int EPI>
__global__ __launch_bounds__(512, 2) void gemm8p_kernel(
    const __bf16* __restrict__ A, const __bf16* __restrict__ B,
    const float* __restrict__ b0, const float* __restrict__ b1, const float* __restrict__ b2,
    __bf16* __restrict__ o0, __bf16* __restrict__ o1, __bf16* __restrict__ o2,
    float* __restrict__ fout)
{
  constexpr int MF = (EPI == 0) ? 4 : 2;
  constexpr int MROWS = MF * 64;
  __shared__ __align__(16) __bf16 As[2][MROWS * 64];
  __shared__ __align__(16) __bf16 Bs[2][256 * 64];
  __shared__ float tcos[640], tsin[640];
  const int tid = threadIdx.x;
  if (EPI == 0) {
    for (int i = tid; i < 640; i += 512) {
      int pos, jj = i & 15;
      if (i < 128)      pos = i >> 4;
      else if (i < 384) pos = (i - 128) >> 4;
      else              pos = (i - 384) >> 4;
      const float invf = exp2f(-(float)jj * 0.83048202372184059f); // 10000^(-jj/16)
      float s, c;
      sincosf((float)pos * invf, &s, &c);
      tcos[i] = c; tsin[i] = s;
    }
  }
  const int wid = tid >> 6, l = tid & 63;
  const int lq = l & 15, lg = l >> 4;
  const int wm = wid >> 2, wn = wid & 3;
  const int bid = blockIdx.x;
  const int xcd = bid & 7, local = bid >> 3;
  int m0, n0;
  if (EPI == 0) {                                 // 864 blocks: 32 m x 27 n
    m0 = (xcd * 4 + (local & 3)) * 256;
    n0 = (local >> 2) * 256;
  } else {                                        // 576 blocks: 64 m x 9 n
    m0 = (xcd * 8 + (local & 7)) * 128;
    n0 = (local >> 3) * 256;
  }
  const int srow = tid >> 3;
  const int schunk = ((tid & 7) ^ (srow & 7)) * 8;
  const int dslot = (tid & 7) * 8;
  const int laneA0 = lq * 128 + ((lg * 16) ^ ((lq & 7) << 4));
  const int laneA1 = lq * 128 + ((64 + lg * 16) ^ ((lq & 7) << 4));

  f32x4 acc[2 * MF][4] = {};
  bf16x8 a[MF][2], bq[2][2][2];

  stage_half<MF>(A, As[0], m0, 0, srow, schunk, dslot);
  stage_half<4>(B, Bs[0], n0, 0, srow, schunk, dslot);
  stage_half<MF>(A, As[1], m0, 64, srow, schunk, dslot);
  stage_half<4>(B, Bs[1], n0, 64, srow, schunk, dslot);
  if (EPI == 0) asm volatile("s_waitcnt vmcnt(8)" ::: "memory");
  else          asm volatile("s_waitcnt vmcnt(6)" ::: "memory");
  __builtin_amdgcn_s_barrier();

  const char* a0p = (const char*)&As[0][0];
  const char* b0p = (const char*)&Bs[0][0];
  const char* a1p = (const char*)&As[1][0];
  const char* b1p = (const char*)&Bs[1][0];

#define TILE_STAGED(AP, BP, SA, SB, KN)                                          \
  phase8<MF, 0, 0, true,  true >(AP, BP, wm, wn, laneA0, laneA1, a, bq, acc);    \
  phase8<MF, 0, 1, false, true >(AP, BP, wm, wn, laneA0, laneA1, a, bq, acc);    \
  stage_half<4>(B, SB, n0, KN, srow, schunk, dslot);                             \
  phase8<MF, 1, 1, true,  false>(AP, BP, wm, wn, laneA0, laneA1, a, bq, acc);    \
  stage_half<MF>(A, SA, m0, KN, srow, schunk, dslot);                            \
  phase8<MF, 1, 0, false, false>(AP, BP, wm, wn, laneA0, laneA1, a, bq, acc);    \
  if (EPI == 0) asm volatile("s_waitcnt vmcnt(8)" ::: "memory");                 \
  else          asm volatile("s_waitcnt vmcnt(6)" ::: "memory");                 \
  __builtin_amdgcn_s_barrier();

#define TILE_PLAIN(AP, BP)                                                       \
  phase8<MF, 0, 0, true,  true >(AP, BP, wm, wn, laneA0, laneA1, a, bq, acc);    \
  phase8<MF, 0, 1, false, true >(AP, BP, wm, wn, laneA0, laneA1, a, bq, acc);    \
  phase8<MF, 1, 1, true,  false>(AP, BP, wm, wn, laneA0, laneA1, a, bq, acc);    \
  phase8<MF, 1, 0, false, false>(AP, BP, wm, wn, laneA0, laneA1, a, bq, acc);

  for (int tt = 0; tt < 34; tt += 2) {
    TILE_STAGED(a0p, b0p, As[0], Bs[0], (tt + 2) * 64)
    TILE_STAGED(a1p, b1p, As[1], Bs[1], (tt + 3) * 64)
  }
  TILE_PLAIN(a0p, b0p)
  asm volatile("s_waitcnt vmcnt(0)" ::: "memory");
  __builtin_amdgcn_s_barrier();
  TILE_PLAIN(a1p, b1p)
#undef TILE_STAGED
#undef TILE_PLAIN

  if (EPI == 0) {
    const int mat = n0 / DIM;
    const int nb = n0 - mat * DIM;
    const float* bias = (mat == 0) ? b0 : (mat == 1) ? b1 : b2;
    __bf16* outp = (mat == 0) ? o0 : (mat == 1) ? o1 : o2;
#pragma unroll
    for (int mr = 0; mr < 8; ++mr) {
      const int gq = (m0 + wm * 128 + mr * 16) >> 4;
      const int si = gq * 4 + lg;
      const int pos3[3] = { si >> 8, (si >> 4) & 15, si & 15 };
#pragma unroll
      for (int p = 0; p < 2; ++p) {
        const int nlo = nb + wn * 64 + (2 * p) * 16 + lq;
        const int nhi = nlo + 16;
        const int hlo = nlo / HD, dlo = nlo - hlo * HD;
        const int hhi = nhi / HD, dhi = nhi - hhi * HD;
        const float blo = bias[nlo], bhi = bias[nhi];
        float c = 1.f, s = 0.f;
        if (mat < 2) {
          const int cix = dlo >> 5;
          const int toff = ((cix == 0) ? 0 : (cix == 1) ? 128 : 384) + pos3[cix] * 16 + lq;
          c = tcos[toff]; s = tsin[toff];
        }
#pragma unroll
        for (int r = 0; r < 4; ++r) {
          const int bp = lg * 4 + r;
          const float x1 = acc[mr][2 * p][r] + blo;
          const float x2 = acc[mr][2 * p + 1][r] + bhi;
          float y1 = x1, y2 = x2;
          if (mat < 2) { y1 = x1 * c - x2 * s; y2 = x2 * c + x1 * s; }
          outp[((size_t)(bp * NH + hlo) * SPS + gq) * HD + dlo] = (__bf16)y1;
          outp[((size_t)(bp * NH + hhi) * SPS + gq) * HD + dhi] = (__bf16)y2;
        }
      }
    }
  } else {
#pragma unroll
    for (int mr = 0; mr < 4; ++mr) {
      const int rbase = m0 + wm * 64 + mr * 16;
#pragma unroll
      for (int nr = 0; nr < 4; ++nr) {
        const int n = n0 + wn * 64 + nr * 16 + lq;
        const float bia = b0[n];
#pragma unroll
        for (int r = 0; r < 4; ++r)
          fout[(size_t)(rbase + lg * 4 + r) * DIM + n] = acc[mr][nr][r] + bia;
      }
    }
  }
}

// ---- V transpose: [b'h][g][d] -> [b'h][d][g], output PRE-SWIZZLED within each
//      64-key chunk (8-key group ^= d&7) so attn's linear global_load_lds lands
//      bank-conflict-free in LDS (rule: swizzle source+read, never gload dest) ----
__global__ __launch_bounds__(256) void transpose_v_kernel(
    const __bf16* __restrict__ v, __bf16* __restrict__ vT)
{
  __shared__ __bf16 t[96][72];   // [d][g ^ swz], row stride 144B
  const int tid = threadIdx.x, bid = blockIdx.x;
  const int bh = bid >> 3, g0 = (bid & 7) * 64;
  const __bf16* src = v + ((size_t)bh * SPS + g0) * HD;
#pragma unroll
  for (int it = 0; it < 3; ++it) {
    const int lin = it * 256 + tid;
    const int row = lin / 12, c8 = (lin % 12) * 8;
    bf16x8 x = *(const bf16x8*)(src + row * HD + c8);
#pragma unroll
    for (int j = 0; j < 8; ++j) {
      const int d = c8 + j;
      t[d][row ^ ((d & 7) << 3)] = x[j];
    }
  }
  __syncthreads();
  __bf16* dst = vT + (size_t)bh * HD * SPS + g0;
#pragma unroll
  for (int it = 0; it < 3; ++it) {
    const int lin = it * 256 + tid;
    const int d = lin / 8, gc = (lin % 8) * 8;
    bf16x8 o = *(const bf16x8*)&t[d][gc ^ ((d & 7) << 3)];
    *(bf16x8*)(dst + (size_t)d * SPS + (gc ^ ((d & 7) << 3))) = o;  // pre-swizzled out
  }
}

// ---- flash attention: 4 waves x 16 q-rows, KVBLK=64, defer-max (THR=8).
//      V^T tile double-buffered in LDS via global_load_lds from pre-swizzled vT;
//      stage(t+1) issued after QK(t), gated by counted vmcnt(3) one tile later. ----
__global__ __launch_bounds__(256) void attn_kernel(
    const __bf16* __restrict__ q, const __bf16* __restrict__ k,
    const __bf16* __restrict__ vTs, __bf16* __restrict__ ao)
{
  __shared__ __align__(16) __bf16 Vt[2][96 * 64];  // [d][key^swz], linear gload dest
  __shared__ __bf16 Pl[4][16 * 72];                // per-wave P [q][key]
  const int tid = threadIdx.x;
  const int w = tid >> 6, l = tid & 63;
  const int lq = l & 15, lg = l >> 4;
  const int bid = blockIdx.x;
  const int swz = (bid & 7) * 384 + (bid >> 3);
  const int qt = swz & 7;
  const int h  = (swz >> 3) % NH;
  const int bp = swz / (NH * 8);
  const size_t bh = (size_t)bp * NH + h;
  const __bf16* qb = q + bh * SPS * HD;
  const __bf16* kb = k + bh * SPS * HD;
  const __bf16* vb = vTs + bh * HD * SPS;
  const int vrow = w * 24 + (l >> 3);        // + j*8, wave w owns d-rows [24w,24w+24)
  const int vcol = (l & 7) * 8;
  bf16x8 qf[3];
  {
    const __bf16* qr = qb + (size_t)(qt * 64 + w * 16 + lq) * HD + lg * 8;
    qf[0] = *(const bf16x8*)(qr);
    qf[1] = *(const bf16x8*)(qr + 32);
    qf[2] = *(const bf16x8*)(qr + 64);
  }
  const float sc = 0.10206207261596575f * 1.4426950408889634f; // 96^-0.5 * log2(e)
  float m_run = -1e30f, l_run = 0.f;         // l_run: per-lane partial sum
  f32x4 o[6] = {};
  // prologue: stage tile 0 -> buf0
#pragma unroll
  for (int j = 0; j < 3; ++j)
    gload16(vb + (size_t)(vrow + j * 8) * SPS + vcol,
            &Vt[0][(vrow + j * 8) * 64 + vcol]);

  for (int t = 0; t < 8; ++t) {
    const int cur = t & 1;
    const int kb0 = t * 64;
    __builtin_amdgcn_s_barrier();            // all waves done PV(t-1) on buf[1-cur]
    // ---- QK^T: S^T = K * Q^T (lane owns q = lq) ----
    f32x4 st[4];
    __builtin_amdgcn_s_setprio(1);
#pragma unroll
    for (int t2 = 0; t2 < 4; ++t2) {
      const __bf16* kr = kb + (size_t)(kb0 + t2 * 16 + lq) * HD + lg * 8;
      bf16x8 k0f = *(const bf16x8*)(kr);
      bf16x8 k1f = *(const bf16x8*)(kr + 32);
      bf16x8 k2f = *(const bf16x8*)(kr + 64);
      f32x4 s = {};
      s = __builtin_amdgcn_mfma_f32_16x16x32_bf16(k0f, qf[0], s, 0, 0, 0);
      s = __builtin_amdgcn_mfma_f32_16x16x32_bf16(k1f, qf[1], s, 0, 0, 0);
      s = __builtin_amdgcn_mfma_f32_16x16x32_bf16(k2f, qf[2], s, 0, 0, 0);
      st[t2] = s;
    }
    __builtin_amdgcn_s_setprio(0);
    __builtin_amdgcn_sched_barrier(0);       // keep stage issue AFTER K loads
    if (t < 7) {
#pragma unroll
      for (int j = 0; j < 3; ++j)
        gload16(vb + (size_t)(vrow + j * 8) * SPS + (kb0 + 64) + vcol,
                &Vt[1 - cur][(vrow + j * 8) * 64 + vcol]);
    }
    __builtin_amdgcn_sched_barrier(0);
    // ---- online softmax, defer-max fast path ----
    float pmax = -1e30f;
#pragma unroll
    for (int t2 = 0; t2 < 4; ++t2)
#pragma unroll
      for (int r = 0; r < 4; ++r) pmax = fmaxf(pmax, st[t2][r]);
    pmax *= sc;
    if (__any(pmax > m_run + 8.f)) {         // rare: ~once per block
      float mn = fmaxf(m_run, pmax);
      mn = fmaxf(mn, __shfl_xor(mn, 16));
      mn = fmaxf(mn, __shfl_xor(mn, 32));
      const float alpha = exp2f(m_run - mn);
      l_run *= alpha;
      float al[4];
#pragma unroll
      for (int r = 0; r < 4; ++r) al[r] = __shfl(alpha, lg * 4 + r);
#pragma unroll
      for (int ni = 0; ni < 6; ++ni)
#pragma unroll
        for (int r = 0; r < 4; ++r) o[ni][r] *= al[r];
      m_run = mn;
    }
#pragma unroll
    for (int t2 = 0; t2 < 4; ++t2) {
      bf16x4 pb;
#pragma unroll
      for (int r = 0; r < 4; ++r) {
        const float p = exp2f(st[t2][r] * sc - m_run);  // bounded by 2^8
        l_run += p;
        pb[r] = (__bf16)p;
      }
      *(bf16x4*)&Pl[w][lq * 72 + t2 * 16 + lg * 4] = pb; // wave-private
    }
    // gate: own stage(t) landed (leaves stage(t+1) in flight); barrier -> global
    if (t < 7) { asm volatile("s_waitcnt vmcnt(3)" ::: "memory"); }
    else       { asm volatile("s_waitcnt vmcnt(0)" ::: "memory"); }
    __builtin_amdgcn_s_barrier();
    // ---- PV from Vt[cur] (swizzled read) ----
#pragma unroll
    for (int ks = 0; ks < 2; ++ks) {
      bf16x8 pa = *(const bf16x8*)&Pl[w][lq * 72 + ks * 32 + lg * 8];
      __builtin_amdgcn_s_setprio(1);
#pragma unroll
      for (int ni = 0; ni < 6; ++ni) {
        const int col = (ks * 32 + lg * 8) ^ ((lq & 7) << 3);
        bf16x8 vf = *(const bf16x8*)&Vt[cur][(ni * 16 + lq) * 64 + col];
        o[ni] = __builtin_amdgcn_mfma_f32_16x16x32_bf16(pa, vf, o[ni], 0, 0, 0);
      }
      __builtin_amdgcn_s_setprio(0);
    }
  }
  l_run += __shfl_xor(l_run, 16);
  l_run += __shfl_xor(l_run, 32);
  float linv[4];
#pragma unroll
  for (int r = 0; r < 4; ++r) linv[r] = 1.f / __shfl(l_run, lg * 4 + r);
#pragma unroll
  for (int ni = 0; ni < 6; ++ni)
#pragma unroll
    for (int r = 0; r < 4; ++r) {
      const int gq = qt * 64 + w * 16 + lg * 4 + r;
      const int d = ni * 16 + lq;
      ao[(size_t)(gq * 16 + bp) * DIM + h * HD + d] = (__bf16)(o[ni][r] * linv[r]);
    }
}

extern "C" void kernel_launch(void* const* d_in, const int* in_sizes, int n_in,
                              void* d_out, int out_size, void* d_ws, size_t ws_size,
                              hipStream_t stream) {
  const float* hs = (const float*)d_in[0];
  const float* wq = (const float*)d_in[1];
  const float* bq = (const float*)d_in[2];
  const float* wk = (const float*)d_in[3];
  const float* bk = (const float*)d_in[4];
  const float* wv = (const float*)d_in[5];
  const float* bv = (const float*)d_in[6];
  const float* wo = (const float*)d_in[7];
  const float* bo = (const float*)d_in[8];
  float* out = (float*)d_out;

  char* ws = (char*)d_ws;
  // live-range-packed layout, total 193,462,272 bytes:
  __bf16* wqkvT = (__bf16*)(ws);                  // prep->qkv
  __bf16* hsb   = (__bf16*)(ws + 31850496);       // prep->qkv
  __bf16* qb    = (__bf16*)(ws + 69599232);       // qkv->attn
  __bf16* kbuf  = (__bf16*)(ws + 107347968);      // qkv->attn
  __bf16* vbuf  = (__bf16*)(ws + 145096704);      // qkv->transpose_v
  __bf16* woT   = (__bf16*)(ws + 182845440);      // prep->gemm_out
  __bf16* vbufT = (__bf16*)(ws);                  // transpose_v->attn (over wqkvT+hsb, dead)
  __bf16* ao    = vbuf;                           // attn->gemm_out (vbuf dead)

  prep_kernel<<<23616, 256, 0, stream>>>(hs, wq, wk, wv, wo, hsb, wqkvT, woT);
  gemm8p_kernel<0><<<864, 512, 0, stream>>>(hsb, wqkvT, bq, bk, bv, qb, kbuf, vbuf, nullptr);
  transpose_v_kernel<<<3072, 256, 0, stream>>>(vbuf, vbufT);
  attn_kernel<<<3072, 256, 0, stream>>>(qb, kbuf, vbufT, ao);
  gemm8p_kernel<1><<<576, 512, 0, stream>>>(ao, woT, bo, nullptr, nullptr, nullptr, nullptr, nullptr, out);
}

// Round 9
// 511.998 us; speedup vs baseline: 3.0427x; 1.0217x over previous
//
#include <hip/hip_runtime.h>
#include <hip/hip_bf16.h>

typedef __attribute__((ext_vector_type(8))) __bf16 bf16x8;
typedef __attribute__((ext_vector_type(4))) __bf16 bf16x4;
typedef __attribute__((ext_vector_type(4))) float  f32x4;

#define DIM   2304
#define NH    24
#define HD    96
#define SPS   512

// ---- async global->LDS, 16B per lane (dest = wave-uniform base + lane*16) ----
__device__ __forceinline__ void gload16(const void* gp, void* lp) {
  __builtin_amdgcn_global_load_lds(
      (__attribute__((address_space(1))) void*)(unsigned long long)gp,
      (__attribute__((address_space(3))) void*)lp, 16, 0, 0);
}

// ---- fused prep: weight transpose/cast (blocks 0..5183) + hs cast (rest) ----
__global__ __launch_bounds__(256) void prep_kernel(
    const float* __restrict__ hs,
    const float* __restrict__ wq, const float* __restrict__ wk,
    const float* __restrict__ wv, const float* __restrict__ wo,
    __bf16* __restrict__ hsb, __bf16* __restrict__ wqkvT, __bf16* __restrict__ woT)
{
  __shared__ float t[64][65];
  const int bid = blockIdx.x;
  const int tid = threadIdx.x;
  if (bid < 5184) {
    const int z = bid / 1296;
    const int rest = bid - z * 1296;
    const int n0 = (rest % 36) * 64, k0 = (rest / 36) * 64;
    const float* src = (z == 0) ? wq : (z == 1) ? wk : (z == 2) ? wv : wo;
    __bf16* dst = (z < 3) ? (wqkvT + (size_t)z * DIM * DIM) : woT;
    const int tx = tid & 63, ty = tid >> 6;
#pragma unroll
    for (int j = 0; j < 64; j += 4)
      t[ty + j][tx] = src[(size_t)(k0 + ty + j) * DIM + n0 + tx];
    __syncthreads();
#pragma unroll
    for (int j = 0; j < 64; j += 4)
      dst[(size_t)(n0 + ty + j) * DIM + k0 + tx] = (__bf16)t[tx][ty + j];
  } else {
    const int i = (bid - 5184) * 256 + tid;
    const float4 f = ((const float4*)hs)[i];
    bf16x4 o = { (__bf16)f.x, (__bf16)f.y, (__bf16)f.z, (__bf16)f.w };
    ((bf16x4*)hsb)[i] = o;
  }
}

// ================= 8-phase GEMM, counted-vmcnt pipeline (r4 schedule) =================
// Remainder-split grids: each launch is an exact number of CU rounds (or a single
// short round), eliminating the 12-25% makespan quantization of 864/576-block grids.
// GRID 0: qkv main   768 blocks, 256x256 (MF=4), ng<24        (exactly 3 rounds)
// GRID 1: qkv tail   192 blocks, 128x256 (MF=2), ng 24..26    (one T/2 round)
// GRID 2: out  main  512 blocks, 128x256 (MF=2), ng<8         (exactly 2 rounds)
// GRID 3: out  tail  128 blocks,  64x256 (MF=1), ng=8         (one T/2 round)

template<int NJ>
__device__ __forceinline__ void stage_half(
    const __bf16* __restrict__ X, __bf16* lX, int r0, int k0,
    int srow, int schunk, int dslot)
{
#pragma unroll
  for (int j = 0; j < NJ; ++j)
    gload16(X + (size_t)(r0 + j * 64 + srow) * DIM + k0 + schunk,
            lX + (j * 64 + srow) * 64 + dslot);
}

template<int MF, int H, int Q, bool LA, bool LB>
__device__ __forceinline__ void phase8(
    const char* ab, const char* bb, int wm, int wn, int laneA0, int laneA1,
    bf16x8 (&a)[MF][2], bf16x8 (&bq)[2][2][2], f32x4 (&acc)[2 * MF][4])
{
  if (LA) {
#pragma unroll
    for (int fm = 0; fm < MF; ++fm) {
      a[fm][0] = *(const bf16x8*)(ab + (wm * (MF * 32) + H * (MF * 16) + fm * 16) * 128 + laneA0);
      a[fm][1] = *(const bf16x8*)(ab + (wm * (MF * 32) + H * (MF * 16) + fm * 16) * 128 + laneA1);
    }
  }
  if (LB) {
#pragma unroll
    for (int fn = 0; fn < 2; ++fn) {
      bq[Q][fn][0] = *(const bf16x8*)(bb + (wn * 64 + Q * 32 + fn * 16) * 128 + laneA0);
      bq[Q][fn][1] = *(const bf16x8*)(bb + (wn * 64 + Q * 32 + fn * 16) * 128 + laneA1);
    }
  }
  __builtin_amdgcn_s_barrier();
  asm volatile("s_waitcnt lgkmcnt(0)" ::: "memory");
  __builtin_amdgcn_s_setprio(1);
#pragma unroll
  for (int fm = 0; fm < MF; ++fm)
#pragma unroll
    for (int fn = 0; fn < 2; ++fn)
#pragma unroll
      for (int kk = 0; kk < 2; ++kk)
        acc[H * MF + fm][Q * 2 + fn] = __builtin_amdgcn_mfma_f32_16x16x32_bf16(
            a[fm][kk], bq[Q][fn][kk], acc[H * MF + fm][Q * 2 + fn], 0, 0, 0);
  __builtin_amdgcn_s_setprio(0);
  __builtin_amdgcn_s_barrier();
}

template<int EPI, int MF, int GRID>
__global__ __launch_bounds__(512, 2) void gemm8p_kernel(
    const __bf16* __restrict__ A, const __bf16* __restrict__ B,
    const float* __restrict__ b0, const float* __restrict__ b1, const float* __restrict__ b2,
    __bf16* __restrict__ o0, __bf16* __restrict__ o1, __bf16* __restrict__ o2,
    float* __restrict__ fout)
{
  constexpr int MROWS = MF * 64;
  constexpr int VG = MF + 4;                      // steady vmcnt gate
  __shared__ __align__(16) __bf16 As[2][MROWS * 64];
  __shared__ __align__(16) __bf16 Bs[2][256 * 64];
  __shared__ float tcos[640], tsin[640];
  const int tid = threadIdx.x;
  if (EPI == 0) {
    for (int i = tid; i < 640; i += 512) {
      int pos, jj = i & 15;
      if (i < 128)      pos = i >> 4;
      else if (i < 384) pos = (i - 128) >> 4;
      else              pos = (i - 384) >> 4;
      const float invf = exp2f(-(float)jj * 0.83048202372184059f); // 10000^(-jj/16)
      float s, c;
      sincosf((float)pos * invf, &s, &c);
      tcos[i] = c; tsin[i] = s;
    }
  }
  const int wid = tid >> 6, l = tid & 63;
  const int lq = l & 15, lg = l >> 4;
  const int wm = wid >> 2, wn = wid & 3;
  const int bid = blockIdx.x;
  const int xcd = bid & 7, local = bid >> 3;
  int m0, n0;
  if (GRID == 0) {        // 768: 32 m x 24 n, 256-tall
    m0 = (xcd * 4 + (local & 3)) * 256;
    n0 = (local >> 2) * 256;
  } else if (GRID == 1) { // 192: 64 m-halves x 3 n (ng 24..26), 128-tall
    m0 = (xcd * 4 + ((local >> 1) & 3)) * 256 + (local & 1) * 128;
    n0 = (24 + (local >> 3)) * 256;
  } else if (GRID == 2) { // 512: 64 m x 8 n, 128-tall
    m0 = (xcd * 8 + (local & 7)) * 128;
    n0 = (local >> 3) * 256;
  } else {                // 128: 128 m-halves x 1 n (ng 8), 64-tall
    m0 = (xcd * 8 + (local >> 1)) * 128 + (local & 1) * 64;
    n0 = 2048;
  }
  const int srow = tid >> 3;
  const int schunk = ((tid & 7) ^ (srow & 7)) * 8;
  const int dslot = (tid & 7) * 8;
  const int laneA0 = lq * 128 + ((lg * 16) ^ ((lq & 7) << 4));
  const int laneA1 = lq * 128 + ((64 + lg * 16) ^ ((lq & 7) << 4));

  f32x4 acc[2 * MF][4] = {};
  bf16x8 a[MF][2], bq[2][2][2];

  stage_half<MF>(A, As[0], m0, 0, srow, schunk, dslot);
  stage_half<4>(B, Bs[0], n0, 0, srow, schunk, dslot);
  stage_half<MF>(A, As[1], m0, 64, srow, schunk, dslot);
  stage_half<4>(B, Bs[1], n0, 64, srow, schunk, dslot);
  asm volatile("s_waitcnt vmcnt(%0)" :: "n"(VG) : "memory");
  __builtin_amdgcn_s_barrier();

  const char* a0p = (const char*)&As[0][0];
  const char* b0p = (const char*)&Bs[0][0];
  const char* a1p = (const char*)&As[1][0];
  const char* b1p = (const char*)&Bs[1][0];

#define TILE_STAGED(AP, BP, SA, SB, KN)                                          \
  phase8<MF, 0, 0, true,  true >(AP, BP, wm, wn, laneA0, laneA1, a, bq, acc);    \
  phase8<MF, 0, 1, false, true >(AP, BP, wm, wn, laneA0, laneA1, a, bq, acc);    \
  stage_half<4>(B, SB, n0, KN, srow, schunk, dslot);                             \
  phase8<MF, 1, 1, true,  false>(AP, BP, wm, wn, laneA0, laneA1, a, bq, acc);    \
  stage_half<MF>(A, SA, m0, KN, srow, schunk, dslot);                            \
  phase8<MF, 1, 0, false, false>(AP, BP, wm, wn, laneA0, laneA1, a, bq, acc);    \
  asm volatile("s_waitcnt vmcnt(%0)" :: "n"(VG) : "memory");                     \
  __builtin_amdgcn_s_barrier();

#define TILE_PLAIN(AP, BP)                                                       \
  phase8<MF, 0, 0, true,  true >(AP, BP, wm, wn, laneA0, laneA1, a, bq, acc);    \
  phase8<MF, 0, 1, false, true >(AP, BP, wm, wn, laneA0, laneA1, a, bq, acc);    \
  phase8<MF, 1, 1, true,  false>(AP, BP, wm, wn, laneA0, laneA1, a, bq, acc);    \
  phase8<MF, 1, 0, false, false>(AP, BP, wm, wn, laneA0, laneA1, a, bq, acc);

  for (int tt = 0; tt < 34; tt += 2) {
    TILE_STAGED(a0p, b0p, As[0], Bs[0], (tt + 2) * 64)
    TILE_STAGED(a1p, b1p, As[1], Bs[1], (tt + 3) * 64)
  }
  TILE_PLAIN(a0p, b0p)
  asm volatile("s_waitcnt vmcnt(0)" ::: "memory");
  __builtin_amdgcn_s_barrier();
  TILE_PLAIN(a1p, b1p)
#undef TILE_STAGED
#undef TILE_PLAIN

  if (EPI == 0) {
    const int mat = n0 / DIM;
    const int nb = n0 - mat * DIM;
    const float* bias = (mat == 0) ? b0 : (mat == 1) ? b1 : b2;
    __bf16* outp = (mat == 0) ? o0 : (mat == 1) ? o1 : o2;
#pragma unroll
    for (int mr = 0; mr < 2 * MF; ++mr) {
      const int gq = (m0 + wm * (MF * 32) + mr * 16) >> 4;
      const int si = gq * 4 + lg;
      const int pos3[3] = { si >> 8, (si >> 4) & 15, si & 15 };
#pragma unroll
      for (int p = 0; p < 2; ++p) {
        const int nlo = nb + wn * 64 + (2 * p) * 16 + lq;
        const int nhi = nlo + 16;
        const int hlo = nlo / HD, dlo = nlo - hlo * HD;
        const int hhi = nhi / HD, dhi = nhi - hhi * HD;
        const float blo = bias[nlo], bhi = bias[nhi];
        float c = 1.f, s = 0.f;
        if (mat < 2) {
          const int cix = dlo >> 5;
          const int toff = ((cix == 0) ? 0 : (cix == 1) ? 128 : 384) + pos3[cix] * 16 + lq;
          c = tcos[toff]; s = tsin[toff];
        }
#pragma unroll
        for (int r = 0; r < 4; ++r) {
          const int bp = lg * 4 + r;
          const float x1 = acc[mr][2 * p][r] + blo;
          const float x2 = acc[mr][2 * p + 1][r] + bhi;
          float y1 = x1, y2 = x2;
          if (mat < 2) { y1 = x1 * c - x2 * s; y2 = x2 * c + x1 * s; }
          outp[((size_t)(bp * NH + hlo) * SPS + gq) * HD + dlo] = (__bf16)y1;
          outp[((size_t)(bp * NH + hhi) * SPS + gq) * HD + dhi] = (__bf16)y2;
        }
      }
    }
  } else {
#pragma unroll
    for (int mr = 0; mr < 2 * MF; ++mr) {
      const int rbase = m0 + wm * (MF * 32) + mr * 16;
#pragma unroll
      for (int nr = 0; nr < 4; ++nr) {
        const int n = n0 + wn * 64 + nr * 16 + lq;
        const float bia = b0[n];
#pragma unroll
        for (int r = 0; r < 4; ++r)
          fout[(size_t)(rbase + lg * 4 + r) * DIM + n] = acc[mr][nr][r] + bia;
      }
    }
  }
}

// ---- V transpose: [b'h][g][d] -> [b'h][d][g], output PRE-SWIZZLED within each
//      64-key chunk (8-key group ^= d&7) so attn's linear global_load_lds lands
//      bank-conflict-free in LDS (rule: swizzle source+read, never gload dest) ----
__global__ __launch_bounds__(256) void transpose_v_kernel(
    const __bf16* __restrict__ v, __bf16* __restrict__ vT)
{
  __shared__ __bf16 t[96][72];   // [d][g ^ swz], row stride 144B
  const int tid = threadIdx.x, bid = blockIdx.x;
  const int bh = bid >> 3, g0 = (bid & 7) * 64;
  const __bf16* src = v + ((size_t)bh * SPS + g0) * HD;
#pragma unroll
  for (int it = 0; it < 3; ++it) {
    const int lin = it * 256 + tid;
    const int row = lin / 12, c8 = (lin % 12) * 8;
    bf16x8 x = *(const bf16x8*)(src + row * HD + c8);
#pragma unroll
    for (int j = 0; j < 8; ++j) {
      const int d = c8 + j;
      t[d][row ^ ((d & 7) << 3)] = x[j];
    }
  }
  __syncthreads();
  __bf16* dst = vT + (size_t)bh * HD * SPS + g0;
#pragma unroll
  for (int it = 0; it < 3; ++it) {
    const int lin = it * 256 + tid;
    const int d = lin / 8, gc = (lin % 8) * 8;
    bf16x8 o = *(const bf16x8*)&t[d][gc ^ ((d & 7) << 3)];
    *(bf16x8*)(dst + (size_t)d * SPS + (gc ^ ((d & 7) << 3))) = o;  // pre-swizzled out
  }
}

// ---- flash attention: 4 waves x 16 q-rows, KVBLK=64, defer-max (THR=8).
//      V^T tile double-buffered in LDS via global_load_lds from pre-swizzled vT;
//      stage(t+1) issued after QK(t), gated by counted vmcnt(3) one tile later. ----
__global__ __launch_bounds__(256) void attn_kernel(
    const __bf16* __restrict__ q, const __bf16* __restrict__ k,
    const __bf16* __restrict__ vTs, __bf16* __restrict__ ao)
{
  __shared__ __align__(16) __bf16 Vt[2][96 * 64];  // [d][key^swz], linear gload dest
  __shared__ __bf16 Pl[4][16 * 72];                // per-wave P [q][key]
  const int tid = threadIdx.x;
  const int w = tid >> 6, l = tid & 63;
  const int lq = l & 15, lg = l >> 4;
  const int bid = blockIdx.x;
  const int swz = (bid & 7) * 384 + (bid >> 3);
  const int qt = swz & 7;
  const int h  = (swz >> 3) % NH;
  const int bp = swz / (NH * 8);
  const size_t bh = (size_t)bp * NH + h;
  const __bf16* qb = q + bh * SPS * HD;
  const __bf16* kb = k + bh * SPS * HD;
  const __bf16* vb = vTs + bh * HD * SPS;
  const int vrow = w * 24 + (l >> 3);        // + j*8, wave w owns d-rows [24w,24w+24)
  const int vcol = (l & 7) * 8;
  bf16x8 qf[3];
  {
    const __bf16* qr = qb + (size_t)(qt * 64 + w * 16 + lq) * HD + lg * 8;
    qf[0] = *(const bf16x8*)(qr);
    qf[1] = *(const bf16x8*)(qr + 32);
    qf[2] = *(const bf16x8*)(qr + 64);
  }
  const float sc = 0.10206207261596575f * 1.4426950408889634f; // 96^-0.5 * log2(e)
  float m_run = -1e30f, l_run = 0.f;         // l_run: per-lane partial sum
  f32x4 o[6] = {};
  // prologue: stage tile 0 -> buf0
#pragma unroll
  for (int j = 0; j < 3; ++j)
    gload16(vb + (size_t)(vrow + j * 8) * SPS + vcol,
            &Vt[0][(vrow + j * 8) * 64 + vcol]);

  for (int t = 0; t < 8; ++t) {
    const int cur = t & 1;
    const int kb0 = t * 64;
    __builtin_amdgcn_s_barrier();            // all waves done PV(t-1) on buf[1-cur]
    // ---- QK^T: S^T = K * Q^T (lane owns q = lq) ----
    f32x4 st[4];
    __builtin_amdgcn_s_setprio(1);
#pragma unroll
    for (int t2 = 0; t2 < 4; ++t2) {
      const __bf16* kr = kb + (size_t)(kb0 + t2 * 16 + lq) * HD + lg * 8;
      bf16x8 k0f = *(const bf16x8*)(kr);
      bf16x8 k1f = *(const bf16x8*)(kr + 32);
      bf16x8 k2f = *(const bf16x8*)(kr + 64);
      f32x4 s = {};
      s = __builtin_amdgcn_mfma_f32_16x16x32_bf16(k0f, qf[0], s, 0, 0, 0);
      s = __builtin_amdgcn_mfma_f32_16x16x32_bf16(k1f, qf[1], s, 0, 0, 0);
      s = __builtin_amdgcn_mfma_f32_16x16x32_bf16(k2f, qf[2], s, 0, 0, 0);
      st[t2] = s;
    }
    __builtin_amdgcn_s_setprio(0);
    __builtin_amdgcn_sched_barrier(0);       // keep stage issue AFTER K loads
    if (t < 7) {
#pragma unroll
      for (int j = 0; j < 3; ++j)
        gload16(vb + (size_t)(vrow + j * 8) * SPS + (kb0 + 64) + vcol,
                &Vt[1 - cur][(vrow + j * 8) * 64 + vcol]);
    }
    __builtin_amdgcn_sched_barrier(0);
    // ---- online softmax, defer-max fast path ----
    float pmax = -1e30f;
#pragma unroll
    for (int t2 = 0; t2 < 4; ++t2)
#pragma unroll
      for (int r = 0; r < 4; ++r) pmax = fmaxf(pmax, st[t2][r]);
    pmax *= sc;
    if (__any(pmax > m_run + 8.f)) {         // rare: ~once per block
      float mn = fmaxf(m_run, pmax);
      mn = fmaxf(mn, __shfl_xor(mn, 16));
      mn = fmaxf(mn, __shfl_xor(mn, 32));
      const float alpha = exp2f(m_run - mn);
      l_run *= alpha;
      float al[4];
#pragma unroll
      for (int r = 0; r < 4; ++r) al[r] = __shfl(alpha, lg * 4 + r);
#pragma unroll
      for (int ni = 0; ni < 6; ++ni)
#pragma unroll
        for (int r = 0; r < 4; ++r) o[ni][r] *= al[r];
      m_run = mn;
    }
#pragma unroll
    for (int t2 = 0; t2 < 4; ++t2) {
      bf16x4 pb;
#pragma unroll
      for (int r = 0; r < 4; ++r) {
        const float p = exp2f(st[t2][r] * sc - m_run);  // bounded by 2^8
        l_run += p;
        pb[r] = (__bf16)p;
      }
      *(bf16x4*)&Pl[w][lq * 72 + t2 * 16 + lg * 4] = pb; // wave-private
    }
    // gate: own stage(t) landed (leaves stage(t+1) in flight); barrier -> global
    if (t < 7) { asm volatile("s_waitcnt vmcnt(3)" ::: "memory"); }
    else       { asm volatile("s_waitcnt vmcnt(0)" ::: "memory"); }
    __builtin_amdgcn_s_barrier();
    // ---- PV from Vt[cur] (swizzled read) ----
#pragma unroll
    for (int ks = 0; ks < 2; ++ks) {
      bf16x8 pa = *(const bf16x8*)&Pl[w][lq * 72 + ks * 32 + lg * 8];
      __builtin_amdgcn_s_setprio(1);
#pragma unroll
      for (int ni = 0; ni < 6; ++ni) {
        const int col = (ks * 32 + lg * 8) ^ ((lq & 7) << 3);
        bf16x8 vf = *(const bf16x8*)&Vt[cur][(ni * 16 + lq) * 64 + col];
        o[ni] = __builtin_amdgcn_mfma_f32_16x16x32_bf16(pa, vf, o[ni], 0, 0, 0);
      }
      __builtin_amdgcn_s_setprio(0);
    }
  }
  l_run += __shfl_xor(l_run, 16);
  l_run += __shfl_xor(l_run, 32);
  float linv[4];
#pragma unroll
  for (int r = 0; r < 4; ++r) linv[r] = 1.f / __shfl(l_run, lg * 4 + r);
#pragma unroll
  for (int ni = 0; ni < 6; ++ni)
#pragma unroll
    for (int r = 0; r < 4; ++r) {
      const int gq = qt * 64 + w * 16 + lg * 4 + r;
      const int d = ni * 16 + lq;
      ao[(size_t)(gq * 16 + bp) * DIM + h * HD + d] = (__bf16)(o[ni][r] * linv[r]);
    }
}

extern "C" void kernel_launch(void* const* d_in, const int* in_sizes, int n_in,
                              void* d_out, int out_size, void* d_ws, size_t ws_size,
                              hipStream_t stream) {
  const float* hs = (const float*)d_in[0];
  const float* wq = (const float*)d_in[1];
  const float* bq = (const float*)d_in[2];
  const float* wk = (const float*)d_in[3];
  const float* bk = (const float*)d_in[4];
  const float* wv = (const float*)d_in[5];
  const float* bv = (const float*)d_in[6];
  const float* wo = (const float*)d_in[7];
  const float* bo = (const float*)d_in[8];
  float* out = (float*)d_out;

  char* ws = (char*)d_ws;
  // live-range-packed layout, total 193,462,272 bytes:
  __bf16* wqkvT = (__bf16*)(ws);                  // prep->qkv
  __bf16* hsb   = (__bf16*)(ws + 31850496);       // prep->qkv
  __bf16* qb    = (__bf16*)(ws + 69599232);       // qkv->attn
  __bf16* kbuf  = (__bf16*)(ws + 107347968);      // qkv->attn
  __bf16* vbuf  = (__bf16*)(ws + 145096704);      // qkv->transpose_v
  __bf16* woT   = (__bf16*)(ws + 182845440);      // prep->gemm_out
  __bf16* vbufT = (__bf16*)(ws);                  // transpose_v->attn (over wqkvT+hsb, dead)
  __bf16* ao    = vbuf;                           // attn->gemm_out (vbuf dead)

  prep_kernel<<<23616, 256, 0, stream>>>(hs, wq, wk, wv, wo, hsb, wqkvT, woT);
  gemm8p_kernel<0, 4, 0><<<768, 512, 0, stream>>>(hsb, wqkvT, bq, bk, bv, qb, kbuf, vbuf, nullptr);
  gemm8p_kernel<0, 2, 1><<<192, 512, 0, stream>>>(hsb, wqkvT, bq, bk, bv, qb, kbuf, vbuf, nullptr);
  transpose_v_kernel<<<3072, 256, 0, stream>>>(vbuf, vbufT);
  attn_kernel<<<3072, 256, 0, stream>>>(qb, kbuf, vbufT, ao);
  gemm8p_kernel<1, 2, 2><<<512, 512, 0, stream>>>(ao, woT, bo, nullptr, nullptr, nullptr, nullptr, nullptr, out);
  gemm8p_kernel<1, 1, 3><<<128, 512, 0, stream>>>(ao, woT, bo, nullptr, nullptr, nullptr, nullptr, nullptr, out);
}

// Round 10
// 492.149 us; speedup vs baseline: 3.1654x; 1.0403x over previous
//
#include <hip/hip_runtime.h>
#include <hip/hip_bf16.h>

typedef __attribute__((ext_vector_type(8))) __bf16 bf16x8;
typedef __attribute__((ext_vector_type(4))) __bf16 bf16x4;
typedef __attribute__((ext_vector_type(4))) float  f32x4;

#define DIM   2304
#define NH    24
#define HD    96
#define SPS   512

// ---- async global->LDS, 16B per lane (dest = wave-uniform base + lane*16) ----
__device__ __forceinline__ void gload16(const void* gp, void* lp) {
  __builtin_amdgcn_global_load_lds(
      (__attribute__((address_space(1))) void*)(unsigned long long)gp,
      (__attribute__((address_space(3))) void*)lp, 16, 0, 0);
}

// ---- fused prep: weight transpose/cast (blocks 0..5183) + hs cast (rest) ----
__global__ __launch_bounds__(256) void prep_kernel(
    const float* __restrict__ hs,
    const float* __restrict__ wq, const float* __restrict__ wk,
    const float* __restrict__ wv, const float* __restrict__ wo,
    __bf16* __restrict__ hsb, __bf16* __restrict__ wqkvT, __bf16* __restrict__ woT)
{
  __shared__ float t[64][65];
  const int bid = blockIdx.x;
  const int tid = threadIdx.x;
  if (bid < 5184) {
    const int z = bid / 1296;
    const int rest = bid - z * 1296;
    const int n0 = (rest % 36) * 64, k0 = (rest / 36) * 64;
    const float* src = (z == 0) ? wq : (z == 1) ? wk : (z == 2) ? wv : wo;
    __bf16* dst = (z < 3) ? (wqkvT + (size_t)z * DIM * DIM) : woT;
    const int tx = tid & 63, ty = tid >> 6;
#pragma unroll
    for (int j = 0; j < 64; j += 4)
      t[ty + j][tx] = src[(size_t)(k0 + ty + j) * DIM + n0 + tx];
    __syncthreads();
#pragma unroll
    for (int j = 0; j < 64; j += 4)
      dst[(size_t)(n0 + ty + j) * DIM + k0 + tx] = (__bf16)t[tx][ty + j];
  } else {
    const int i = (bid - 5184) * 256 + tid;
    const float4 f = ((const float4*)hs)[i];
    bf16x4 o = { (__bf16)f.x, (__bf16)f.y, (__bf16)f.z, (__bf16)f.w };
    ((bf16x4*)hsb)[i] = o;
  }
}

// ====== 8-phase GEMM, counted-vmcnt + early-issue ds_reads (register-neutral) ======
// Read/MFMA overlap WITHOUT extra registers: bq1's reads issued in P0 (drained by
// compiler's counted wait before P1's MFMA); a[] H1 reads issued right after their
// last H0 consumer (P1's MFMA), drained before P2. No manual lgkmcnt -- reads are
// compiler-visible, hipcc emits counted waits. Stage/vmcnt-gate placement as r9.
// GRID 0: qkv main 768 blk 256x256 (MF=4) | 1: qkv tail 192 blk 128x256 (MF=2)
// GRID 2: out main 512 blk 128x256 (MF=2) | 3: out tail 128 blk 64x256 (MF=1)

template<int NJ>
__device__ __forceinline__ void stage_half(
    const __bf16* __restrict__ X, __bf16* lX, int r0, int k0,
    int srow, int schunk, int dslot)
{
#pragma unroll
  for (int j = 0; j < NJ; ++j)
    gload16(X + (size_t)(r0 + j * 64 + srow) * DIM + k0 + schunk,
            lX + (j * 64 + srow) * 64 + dslot);
}

template<int EPI, int MF, int GRID>
__global__ __launch_bounds__(512, 2) void gemm8p_kernel(
    const __bf16* __restrict__ A, const __bf16* __restrict__ B,
    const float* __restrict__ b0, const float* __restrict__ b1, const float* __restrict__ b2,
    __bf16* __restrict__ o0, __bf16* __restrict__ o1, __bf16* __restrict__ o2,
    float* __restrict__ fout)
{
  constexpr int MROWS = MF * 64;
  constexpr int VG = MF + 4;                      // steady vmcnt gate
  __shared__ __align__(16) __bf16 As[2][MROWS * 64];
  __shared__ __align__(16) __bf16 Bs[2][256 * 64];
  __shared__ float tcos[640], tsin[640];
  const int tid = threadIdx.x;
  if (EPI == 0) {
    for (int i = tid; i < 640; i += 512) {
      int pos, jj = i & 15;
      if (i < 128)      pos = i >> 4;
      else if (i < 384) pos = (i - 128) >> 4;
      else              pos = (i - 384) >> 4;
      const float invf = exp2f(-(float)jj * 0.83048202372184059f); // 10000^(-jj/16)
      float s, c;
      sincosf((float)pos * invf, &s, &c);
      tcos[i] = c; tsin[i] = s;
    }
  }
  const int wid = tid >> 6, l = tid & 63;
  const int lq = l & 15, lg = l >> 4;
  const int wm = wid >> 2, wn = wid & 3;
  const int bid = blockIdx.x;
  const int xcd = bid & 7, local = bid >> 3;
  int m0, n0;
  if (GRID == 0) {        // 768: 32 m x 24 n, 256-tall
    m0 = (xcd * 4 + (local & 3)) * 256;
    n0 = (local >> 2) * 256;
  } else if (GRID == 1) { // 192: 64 m-halves x 3 n (ng 24..26), 128-tall
    m0 = (xcd * 4 + ((local >> 1) & 3)) * 256 + (local & 1) * 128;
    n0 = (24 + (local >> 3)) * 256;
  } else if (GRID == 2) { // 512: 64 m x 8 n, 128-tall
    m0 = (xcd * 8 + (local & 7)) * 128;
    n0 = (local >> 3) * 256;
  } else {                // 128: 128 m-halves x 1 n (ng 8), 64-tall
    m0 = (xcd * 8 + (local >> 1)) * 128 + (local & 1) * 64;
    n0 = 2048;
  }
  const int srow = tid >> 3;
  const int schunk = ((tid & 7) ^ (srow & 7)) * 8;
  const int dslot = (tid & 7) * 8;
  const int laneA0 = lq * 128 + ((lg * 16) ^ ((lq & 7) << 4));
  const int laneA1 = lq * 128 + ((64 + lg * 16) ^ ((lq & 7) << 4));

  f32x4 acc[2 * MF][4] = {};
  bf16x8 a[MF][2], b0r[2][2], b1r[2][2];

#define LOAD_A(APx, Hh) do { _Pragma("unroll")                                   \
  for (int fm = 0; fm < MF; ++fm) {                                              \
    a[fm][0] = *(const bf16x8*)((APx) + (wm * (MF * 32) + (Hh) * (MF * 16) + fm * 16) * 128 + laneA0); \
    a[fm][1] = *(const bf16x8*)((APx) + (wm * (MF * 32) + (Hh) * (MF * 16) + fm * 16) * 128 + laneA1); } } while (0)

#define LOAD_B(dst, BPx, Qq) do { _Pragma("unroll")                              \
  for (int fn = 0; fn < 2; ++fn) {                                               \
    dst[fn][0] = *(const bf16x8*)((BPx) + (wn * 64 + (Qq) * 32 + fn * 16) * 128 + laneA0); \
    dst[fn][1] = *(const bf16x8*)((BPx) + (wn * 64 + (Qq) * 32 + fn * 16) * 128 + laneA1); } } while (0)

#define MFMA_C(bset, Hh, Qq) do { __builtin_amdgcn_s_setprio(1); _Pragma("unroll") \
  for (int fm = 0; fm < MF; ++fm) _Pragma("unroll")                              \
    for (int fn = 0; fn < 2; ++fn) _Pragma("unroll")                             \
      for (int kk = 0; kk < 2; ++kk)                                             \
        acc[(Hh) * MF + fm][(Qq) * 2 + fn] = __builtin_amdgcn_mfma_f32_16x16x32_bf16( \
            a[fm][kk], bset[fn][kk], acc[(Hh) * MF + fm][(Qq) * 2 + fn], 0, 0, 0); \
  __builtin_amdgcn_s_setprio(0); } while (0)

  // prologue: stage tiles 0,1
  stage_half<MF>(A, As[0], m0, 0, srow, schunk, dslot);
  stage_half<4>(B, Bs[0], n0, 0, srow, schunk, dslot);
  stage_half<MF>(A, As[1], m0, 64, srow, schunk, dslot);
  stage_half<4>(B, Bs[1], n0, 64, srow, schunk, dslot);
  asm volatile("s_waitcnt vmcnt(%0)" :: "n"(VG) : "memory");
  __builtin_amdgcn_s_barrier();

  const char* a0p = (const char*)&As[0][0];
  const char* b0p = (const char*)&Bs[0][0];
  const char* a1p = (const char*)&As[1][0];
  const char* b1p = (const char*)&Bs[1][0];

  // tile: reads issued early (bq1 in P0, a-H1 after its last H0 consumer);
  // barriers: (b) P0|P1 pace, (c) pre-stageB [all B-reads drained block-wide],
  // (d) pre-stageA [all A-reads drained], tile-end gate.
#define TILE_STAGED(AP, BP, SA, SB, KN)                                          \
  LOAD_A(AP, 0); LOAD_B(b0r, BP, 0); LOAD_B(b1r, BP, 1);                         \
  __builtin_amdgcn_s_barrier();                                                  \
  MFMA_C(b0r, 0, 0);                                                             \
  __builtin_amdgcn_s_barrier();                                                  \
  MFMA_C(b1r, 0, 1);                                                             \
  LOAD_A(AP, 1);                                                                 \
  __builtin_amdgcn_s_barrier();                                                  \
  stage_half<4>(B, SB, n0, KN, srow, schunk, dslot);                             \
  MFMA_C(b1r, 1, 1);                                                             \
  __builtin_amdgcn_s_barrier();                                                  \
  stage_half<MF>(A, SA, m0, KN, srow, schunk, dslot);                            \
  MFMA_C(b0r, 1, 0);                                                             \
  asm volatile("s_waitcnt vmcnt(%0)" :: "n"(VG) : "memory");                     \
  __builtin_amdgcn_s_barrier();

#define TILE_PLAIN(AP, BP)                                                       \
  LOAD_A(AP, 0); LOAD_B(b0r, BP, 0); LOAD_B(b1r, BP, 1);                         \
  __builtin_amdgcn_s_barrier();                                                  \
  MFMA_C(b0r, 0, 0);                                                             \
  __builtin_amdgcn_s_barrier();                                                  \
  MFMA_C(b1r, 0, 1);                                                             \
  LOAD_A(AP, 1);                                                                 \
  __builtin_amdgcn_s_barrier();                                                  \
  MFMA_C(b1r, 1, 1);                                                             \
  __builtin_amdgcn_s_barrier();                                                  \
  MFMA_C(b0r, 1, 0);

  for (int tt = 0; tt < 34; tt += 2) {
    TILE_STAGED(a0p, b0p, As[0], Bs[0], (tt + 2) * 64)
    TILE_STAGED(a1p, b1p, As[1], Bs[1], (tt + 3) * 64)
  }
  TILE_PLAIN(a0p, b0p)
  asm volatile("s_waitcnt vmcnt(0)" ::: "memory");
  __builtin_amdgcn_s_barrier();
  TILE_PLAIN(a1p, b1p)
#undef TILE_STAGED
#undef TILE_PLAIN
#undef LOAD_A
#undef LOAD_B
#undef MFMA_C

  if (EPI == 0) {
    const int mat = n0 / DIM;
    const int nb = n0 - mat * DIM;
    const float* bias = (mat == 0) ? b0 : (mat == 1) ? b1 : b2;
    __bf16* outp = (mat == 0) ? o0 : (mat == 1) ? o1 : o2;
#pragma unroll
    for (int mr = 0; mr < 2 * MF; ++mr) {
      const int gq = (m0 + wm * (MF * 32) + mr * 16) >> 4;
      const int si = gq * 4 + lg;
      const int pos3[3] = { si >> 8, (si >> 4) & 15, si & 15 };
#pragma unroll
      for (int p = 0; p < 2; ++p) {
        const int nlo = nb + wn * 64 + (2 * p) * 16 + lq;
        const int nhi = nlo + 16;
        const int hlo = nlo / HD, dlo = nlo - hlo * HD;
        const int hhi = nhi / HD, dhi = nhi - hhi * HD;
        const float blo = bias[nlo], bhi = bias[nhi];
        float c = 1.f, s = 0.f;
        if (mat < 2) {
          const int cix = dlo >> 5;
          const int toff = ((cix == 0) ? 0 : (cix == 1) ? 128 : 384) + pos3[cix] * 16 + lq;
          c = tcos[toff]; s = tsin[toff];
        }
#pragma unroll
        for (int r = 0; r < 4; ++r) {
          const int bp = lg * 4 + r;
          const float x1 = acc[mr][2 * p][r] + blo;
          const float x2 = acc[mr][2 * p + 1][r] + bhi;
          float y1 = x1, y2 = x2;
          if (mat < 2) { y1 = x1 * c - x2 * s; y2 = x2 * c + x1 * s; }
          outp[((size_t)(bp * NH + hlo) * SPS + gq) * HD + dlo] = (__bf16)y1;
          outp[((size_t)(bp * NH + hhi) * SPS + gq) * HD + dhi] = (__bf16)y2;
        }
      }
    }
  } else {
#pragma unroll
    for (int mr = 0; mr < 2 * MF; ++mr) {
      const int rbase = m0 + wm * (MF * 32) + mr * 16;
#pragma unroll
      for (int nr = 0; nr < 4; ++nr) {
        const int n = n0 + wn * 64 + nr * 16 + lq;
        const float bia = b0[n];
#pragma unroll
        for (int r = 0; r < 4; ++r)
          fout[(size_t)(rbase + lg * 4 + r) * DIM + n] = acc[mr][nr][r] + bia;
      }
    }
  }
}

// ---- V transpose: [b'h][g][d] -> [b'h][d][g], output PRE-SWIZZLED within each
//      64-key chunk (8-key group ^= d&7) so attn's linear global_load_lds lands
//      bank-conflict-free in LDS ----
__global__ __launch_bounds__(256) void transpose_v_kernel(
    const __bf16* __restrict__ v, __bf16* __restrict__ vT)
{
  __shared__ __bf16 t[96][72];   // [d][g ^ swz], row stride 144B
  const int tid = threadIdx.x, bid = blockIdx.x;
  const int bh = bid >> 3, g0 = (bid & 7) * 64;
  const __bf16* src = v + ((size_t)bh * SPS + g0) * HD;
#pragma unroll
  for (int it = 0; it < 3; ++it) {
    const int lin = it * 256 + tid;
    const int row = lin / 12, c8 = (lin % 12) * 8;
    bf16x8 x = *(const bf16x8*)(src + row * HD + c8);
#pragma unroll
    for (int j = 0; j < 8; ++j) {
      const int d = c8 + j;
      t[d][row ^ ((d & 7) << 3)] = x[j];
    }
  }
  __syncthreads();
  __bf16* dst = vT + (size_t)bh * HD * SPS + g0;
#pragma unroll
  for (int it = 0; it < 3; ++it) {
    const int lin = it * 256 + tid;
    const int d = lin / 8, gc = (lin % 8) * 8;
    bf16x8 o = *(const bf16x8*)&t[d][gc ^ ((d & 7) << 3)];
    *(bf16x8*)(dst + (size_t)d * SPS + (gc ^ ((d & 7) << 3))) = o;  // pre-swizzled out
  }
}

// ---- flash attention: 4 waves x 16 q-rows, KVBLK=64, defer-max (THR=8).
//      BOTH K and V tiles double-buffered in LDS via global_load_lds (K tile is a
//      contiguous 12KB block -> pure linear copy). Stage(t+1) issued at tile top,
//      gated by counted vmcnt(6) -- no global latency on the MFMA path. ----
__global__ __launch_bounds__(256) void attn_kernel(
    const __bf16* __restrict__ q, const __bf16* __restrict__ k,
    const __bf16* __restrict__ vTs, __bf16* __restrict__ ao)
{
  __shared__ __align__(16) __bf16 Kt[2][64 * 96];  // [key][d] linear, 12KB each
  __shared__ __align__(16) __bf16 Vt[2][96 * 64];  // [d][key^swz]
  __shared__ __bf16 Pl[4][16 * 72];                // per-wave P [q][key]
  const int tid = threadIdx.x;
  const int w = tid >> 6, l = tid & 63;
  const int lq = l & 15, lg = l >> 4;
  const int bid = blockIdx.x;
  const int swz = (bid & 7) * 384 + (bid >> 3);
  const int qt = swz & 7;
  const int h  = (swz >> 3) % NH;
  const int bp = swz / (NH * 8);
  const size_t bh = (size_t)bp * NH + h;
  const __bf16* qb = q + bh * SPS * HD;
  const char* kbytes = (const char*)(k + bh * SPS * HD);
  const __bf16* vb = vTs + bh * HD * SPS;
  const int vrow = w * 24 + (l >> 3);
  const int vcol = (l & 7) * 8;
  bf16x8 qf[3];
  {
    const __bf16* qr = qb + (size_t)(qt * 64 + w * 16 + lq) * HD + lg * 8;
    qf[0] = *(const bf16x8*)(qr);
    qf[1] = *(const bf16x8*)(qr + 32);
    qf[2] = *(const bf16x8*)(qr + 64);
  }
  const float sc = 0.10206207261596575f * 1.4426950408889634f; // 96^-0.5 * log2(e)
  float m_run = -1e30f, l_run = 0.f;               // per-lane partial sum
  f32x4 o[6] = {};
  // prologue: stage tile 0 (3 K + 3 V gloads)
#pragma unroll
  for (int j = 0; j < 3; ++j)
    gload16(kbytes + j * 4096 + tid * 16, (char*)&Kt[0][0] + j * 4096 + tid * 16);
#pragma unroll
  for (int j = 0; j < 3; ++j)
    gload16(vb + (size_t)(vrow + j * 8) * SPS + vcol,
            &Vt[0][(vrow + j * 8) * 64 + vcol]);

  for (int t = 0; t < 8; ++t) {
    const int cur = t & 1;
    const int kb0 = t * 64;
    __builtin_amdgcn_s_barrier();                  // PV(t-1) complete block-wide
    if (t < 7) {
#pragma unroll
      for (int j = 0; j < 3; ++j)
        gload16(kbytes + (size_t)(kb0 + 64) * 192 + j * 4096 + tid * 16,
                (char*)&Kt[1 - cur][0] + j * 4096 + tid * 16);
#pragma unroll
      for (int j = 0; j < 3; ++j)
        gload16(vb + (size_t)(vrow + j * 8) * SPS + (kb0 + 64) + vcol,
                &Vt[1 - cur][(vrow + j * 8) * 64 + vcol]);
      asm volatile("s_waitcnt vmcnt(6)" ::: "memory");  // drain stage(t), keep t+1
    } else {
      asm volatile("s_waitcnt vmcnt(0)" ::: "memory");
    }
    __builtin_amdgcn_s_barrier();                  // staged K(t),V(t) visible to all
    // ---- QK^T from Kt[cur]: S^T = K * Q^T (lane owns q = lq) ----
    f32x4 st[4];
    __builtin_amdgcn_s_setprio(1);
#pragma unroll
    for (int t2 = 0; t2 < 4; ++t2) {
      const __bf16* kr = &Kt[cur][(t2 * 16 + lq) * 96 + lg * 8];
      bf16x8 k0f = *(const bf16x8*)(kr);
      bf16x8 k1f = *(const bf16x8*)(kr + 32);
      bf16x8 k2f = *(const bf16x8*)(kr + 64);
      f32x4 s = {};
      s = __builtin_amdgcn_mfma_f32_16x16x32_bf16(k0f, qf[0], s, 0, 0, 0);
      s = __builtin_amdgcn_mfma_f32_16x16x32_bf16(k1f, qf[1], s, 0, 0, 0);
      s = __builtin_amdgcn_mfma_f32_16x16x32_bf16(k2f, qf[2], s, 0, 0, 0);
      st[t2] = s;
    }
    __builtin_amdgcn_s_setprio(0);
    // ---- online softmax, defer-max fast path ----
    float pmax = -1e30f;
#pragma unroll
    for (int t2 = 0; t2 < 4; ++t2)
#pragma unroll
      for (int r = 0; r < 4; ++r) pmax = fmaxf(pmax, st[t2][r]);
    pmax *= sc;
    if (__any(pmax > m_run + 8.f)) {               // rare: ~once per block
      float mn = fmaxf(m_run, pmax);
      mn = fmaxf(mn, __shfl_xor(mn, 16));
      mn = fmaxf(mn, __shfl_xor(mn, 32));
      const float alpha = exp2f(m_run - mn);
      l_run *= alpha;
      float al[4];
#pragma unroll
      for (int r = 0; r < 4; ++r) al[r] = __shfl(alpha, lg * 4 + r);
#pragma unroll
      for (int ni = 0; ni < 6; ++ni)
#pragma unroll
        for (int r = 0; r < 4; ++r) o[ni][r] *= al[r];
      m_run = mn;
    }
#pragma unroll
    for (int t2 = 0; t2 < 4; ++t2) {
      bf16x4 pb;
#pragma unroll
      for (int r = 0; r < 4; ++r) {
        const float p = exp2f(st[t2][r] * sc - m_run);  // bounded by 2^8
        l_run += p;
        pb[r] = (__bf16)p;
      }
      *(bf16x4*)&Pl[w][lq * 72 + t2 * 16 + lg * 4] = pb; // wave-private
    }
    // ---- PV from Vt[cur] (swizzled read); Pl same-wave (compiler lgkm waits) ----
#pragma unroll
    for (int ks = 0; ks < 2; ++ks) {
      bf16x8 pa = *(const bf16x8*)&Pl[w][lq * 72 + ks * 32 + lg * 8];
      __builtin_amdgcn_s_setprio(1);
#pragma unroll
      for (int ni = 0; ni < 6; ++ni) {
        const int col = (ks * 32 + lg * 8) ^ ((lq & 7) << 3);
        bf16x8 vf = *(const bf16x8*)&Vt[cur][(ni * 16 + lq) * 64 + col];
        o[ni] = __builtin_amdgcn_mfma_f32_16x16x32_bf16(pa, vf, o[ni], 0, 0, 0);
      }
      __builtin_amdgcn_s_setprio(0);
    }
  }
  l_run += __shfl_xor(l_run, 16);
  l_run += __shfl_xor(l_run, 32);
  float linv[4];
#pragma unroll
  for (int r = 0; r < 4; ++r) linv[r] = 1.f / __shfl(l_run, lg * 4 + r);
#pragma unroll
  for (int ni = 0; ni < 6; ++ni)
#pragma unroll
    for (int r = 0; r < 4; ++r) {
      const int gq = qt * 64 + w * 16 + lg * 4 + r;
      const int d = ni * 16 + lq;
      ao[(size_t)(gq * 16 + bp) * DIM + h * HD + d] = (__bf16)(o[ni][r] * linv[r]);
    }
}

extern "C" void kernel_launch(void* const* d_in, const int* in_sizes, int n_in,
                              void* d_out, int out_size, void* d_ws, size_t ws_size,
                              hipStream_t stream) {
  const float* hs = (const float*)d_in[0];
  const float* wq = (const float*)d_in[1];
  const float* bq = (const float*)d_in[2];
  const float* wk = (const float*)d_in[3];
  const float* bk = (const float*)d_in[4];
  const float* wv = (const float*)d_in[5];
  const float* bv = (const float*)d_in[6];
  const float* wo = (const float*)d_in[7];
  const float* bo = (const float*)d_in[8];
  float* out = (float*)d_out;

  char* ws = (char*)d_ws;
  // live-range-packed layout, total 193,462,272 bytes:
  __bf16* wqkvT = (__bf16*)(ws);                  // prep->qkv
  __bf16* hsb   = (__bf16*)(ws + 31850496);       // prep->qkv
  __bf16* qb    = (__bf16*)(ws + 69599232);       // qkv->attn
  __bf16* kbuf  = (__bf16*)(ws + 107347968);      // qkv->attn
  __bf16* vbuf  = (__bf16*)(ws + 145096704);      // qkv->transpose_v
  __bf16* woT   = (__bf16*)(ws + 182845440);      // prep->gemm_out
  __bf16* vbufT = (__bf16*)(ws);                  // transpose_v->attn (over wqkvT+hsb, dead)
  __bf16* ao    = vbuf;                           // attn->gemm_out (vbuf dead)

  prep_kernel<<<23616, 256, 0, stream>>>(hs, wq, wk, wv, wo, hsb, wqkvT, woT);
  gemm8p_kernel<0, 4, 0><<<768, 512, 0, stream>>>(hsb, wqkvT, bq, bk, bv, qb, kbuf, vbuf, nullptr);
  gemm8p_kernel<0, 2, 1><<<192, 512, 0, stream>>>(hsb, wqkvT, bq, bk, bv, qb, kbuf, vbuf, nullptr);
  transpose_v_kernel<<<3072, 256, 0, stream>>>(vbuf, vbufT);
  attn_kernel<<<3072, 256, 0, stream>>>(qb, kbuf, vbufT, ao);
  gemm8p_kernel<1, 2, 2><<<512, 512, 0, stream>>>(ao, woT, bo, nullptr, nullptr, nullptr, nullptr, nullptr, out);
  gemm8p_kernel<1, 1, 3><<<128, 512, 0, stream>>>(ao, woT, bo, nullptr, nullptr, nullptr, nullptr, nullptr, out);
}

// Round 11
// 474.051 us; speedup vs baseline: 3.2862x; 1.0382x over previous
//
#include <hip/hip_runtime.h>
#include <hip/hip_bf16.h>

typedef __attribute__((ext_vector_type(8))) __bf16 bf16x8;
typedef __attribute__((ext_vector_type(4))) __bf16 bf16x4;
typedef __attribute__((ext_vector_type(4))) float  f32x4;

#define DIM   2304
#define NH    24
#define HD    96
#define SPS   512

// ---- async global->LDS, 16B per lane (dest = wave-uniform base + lane*16) ----
__device__ __forceinline__ void gload16(const void* gp, void* lp) {
  __builtin_amdgcn_global_load_lds(
      (__attribute__((address_space(1))) void*)(unsigned long long)gp,
      (__attribute__((address_space(3))) void*)lp, 16, 0, 0);
}

// ---- fused prep: weight transpose/cast (blocks 0..5183) + hs cast (rest) ----
__global__ __launch_bounds__(256) void prep_kernel(
    const float* __restrict__ hs,
    const float* __restrict__ wq, const float* __restrict__ wk,
    const float* __restrict__ wv, const float* __restrict__ wo,
    __bf16* __restrict__ hsb, __bf16* __restrict__ wqkvT, __bf16* __restrict__ woT)
{
  __shared__ float t[64][65];
  const int bid = blockIdx.x;
  const int tid = threadIdx.x;
  if (bid < 5184) {
    const int z = bid / 1296;
    const int rest = bid - z * 1296;
    const int n0 = (rest % 36) * 64, k0 = (rest / 36) * 64;
    const float* src = (z == 0) ? wq : (z == 1) ? wk : (z == 2) ? wv : wo;
    __bf16* dst = (z < 3) ? (wqkvT + (size_t)z * DIM * DIM) : woT;
    const int tx = tid & 63, ty = tid >> 6;
#pragma unroll
    for (int j = 0; j < 64; j += 4)
      t[ty + j][tx] = src[(size_t)(k0 + ty + j) * DIM + n0 + tx];
    __syncthreads();
#pragma unroll
    for (int j = 0; j < 64; j += 4)
      dst[(size_t)(n0 + ty + j) * DIM + k0 + tx] = (__bf16)t[tx][ty + j];
  } else {
    const int i = (bid - 5184) * 256 + tid;
    const float4 f = ((const float4*)hs)[i];
    bf16x4 o = { (__bf16)f.x, (__bf16)f.y, (__bf16)f.z, (__bf16)f.w };
    ((bf16x4*)hsb)[i] = o;
  }
}

// ====== 8-phase GEMM, counted-vmcnt + early-issue ds_reads (r10 schedule) ======
// GRID 0: qkv main 768 blk 256x256 (MF=4) | 1: qkv tail 192 blk 128x256 (MF=2)
// GRID 2: out main 512 blk 128x256 (MF=2) | 3: out tail 128 blk 64x256 (MF=1)

template<int NJ>
__device__ __forceinline__ void stage_half(
    const __bf16* __restrict__ X, __bf16* lX, int r0, int k0,
    int srow, int schunk, int dslot)
{
#pragma unroll
  for (int j = 0; j < NJ; ++j)
    gload16(X + (size_t)(r0 + j * 64 + srow) * DIM + k0 + schunk,
            lX + (j * 64 + srow) * 64 + dslot);
}

template<int EPI, int MF, int GRID>
__global__ __launch_bounds__(512, 2) void gemm8p_kernel(
    const __bf16* __restrict__ A, const __bf16* __restrict__ B,
    const float* __restrict__ b0, const float* __restrict__ b1, const float* __restrict__ b2,
    __bf16* __restrict__ o0, __bf16* __restrict__ o1, __bf16* __restrict__ o2,
    float* __restrict__ fout)
{
  constexpr int MROWS = MF * 64;
  constexpr int VG = MF + 4;                      // steady vmcnt gate
  __shared__ __align__(16) __bf16 As[2][MROWS * 64];
  __shared__ __align__(16) __bf16 Bs[2][256 * 64];
  __shared__ float tcos[640], tsin[640];
  const int tid = threadIdx.x;
  if (EPI == 0) {
    for (int i = tid; i < 640; i += 512) {
      int pos, jj = i & 15;
      if (i < 128)      pos = i >> 4;
      else if (i < 384) pos = (i - 128) >> 4;
      else              pos = (i - 384) >> 4;
      const float invf = exp2f(-(float)jj * 0.83048202372184059f); // 10000^(-jj/16)
      float s, c;
      sincosf((float)pos * invf, &s, &c);
      tcos[i] = c; tsin[i] = s;
    }
  }
  const int wid = tid >> 6, l = tid & 63;
  const int lq = l & 15, lg = l >> 4;
  const int wm = wid >> 2, wn = wid & 3;
  const int bid = blockIdx.x;
  const int xcd = bid & 7, local = bid >> 3;
  int m0, n0;
  if (GRID == 0) {        // 768: 32 m x 24 n, 256-tall
    m0 = (xcd * 4 + (local & 3)) * 256;
    n0 = (local >> 2) * 256;
  } else if (GRID == 1) { // 192: 64 m-halves x 3 n (ng 24..26), 128-tall
    m0 = (xcd * 4 + ((local >> 1) & 3)) * 256 + (local & 1) * 128;
    n0 = (24 + (local >> 3)) * 256;
  } else if (GRID == 2) { // 512: 64 m x 8 n, 128-tall
    m0 = (xcd * 8 + (local & 7)) * 128;
    n0 = (local >> 3) * 256;
  } else {                // 128: 128 m-halves x 1 n (ng 8), 64-tall
    m0 = (xcd * 8 + (local >> 1)) * 128 + (local & 1) * 64;
    n0 = 2048;
  }
  const int srow = tid >> 3;
  const int schunk = ((tid & 7) ^ (srow & 7)) * 8;
  const int dslot = (tid & 7) * 8;
  const int laneA0 = lq * 128 + ((lg * 16) ^ ((lq & 7) << 4));
  const int laneA1 = lq * 128 + ((64 + lg * 16) ^ ((lq & 7) << 4));

  f32x4 acc[2 * MF][4] = {};
  bf16x8 a[MF][2], b0r[2][2], b1r[2][2];

#define LOAD_A(APx, Hh) do { _Pragma("unroll")                                   \
  for (int fm = 0; fm < MF; ++fm) {                                              \
    a[fm][0] = *(const bf16x8*)((APx) + (wm * (MF * 32) + (Hh) * (MF * 16) + fm * 16) * 128 + laneA0); \
    a[fm][1] = *(const bf16x8*)((APx) + (wm * (MF * 32) + (Hh) * (MF * 16) + fm * 16) * 128 + laneA1); } } while (0)

#define LOAD_B(dst, BPx, Qq) do { _Pragma("unroll")                              \
  for (int fn = 0; fn < 2; ++fn) {                                               \
    dst[fn][0] = *(const bf16x8*)((BPx) + (wn * 64 + (Qq) * 32 + fn * 16) * 128 + laneA0); \
    dst[fn][1] = *(const bf16x8*)((BPx) + (wn * 64 + (Qq) * 32 + fn * 16) * 128 + laneA1); } } while (0)

#define MFMA_C(bset, Hh, Qq) do { __builtin_amdgcn_s_setprio(1); _Pragma("unroll") \
  for (int fm = 0; fm < MF; ++fm) _Pragma("unroll")                              \
    for (int fn = 0; fn < 2; ++fn) _Pragma("unroll")                             \
      for (int kk = 0; kk < 2; ++kk)                                             \
        acc[(Hh) * MF + fm][(Qq) * 2 + fn] = __builtin_amdgcn_mfma_f32_16x16x32_bf16( \
            a[fm][kk], bset[fn][kk], acc[(Hh) * MF + fm][(Qq) * 2 + fn], 0, 0, 0); \
  __builtin_amdgcn_s_setprio(0); } while (0)

  // prologue: stage tiles 0,1
  stage_half<MF>(A, As[0], m0, 0, srow, schunk, dslot);
  stage_half<4>(B, Bs[0], n0, 0, srow, schunk, dslot);
  stage_half<MF>(A, As[1], m0, 64, srow, schunk, dslot);
  stage_half<4>(B, Bs[1], n0, 64, srow, schunk, dslot);
  asm volatile("s_waitcnt vmcnt(%0)" :: "n"(VG) : "memory");
  __builtin_amdgcn_s_barrier();

  const char* a0p = (const char*)&As[0][0];
  const char* b0p = (const char*)&Bs[0][0];
  const char* a1p = (const char*)&As[1][0];
  const char* b1p = (const char*)&Bs[1][0];

#define TILE_STAGED(AP, BP, SA, SB, KN)                                          \
  LOAD_A(AP, 0); LOAD_B(b0r, BP, 0); LOAD_B(b1r, BP, 1);                         \
  __builtin_amdgcn_s_barrier();                                                  \
  MFMA_C(b0r, 0, 0);                                                             \
  __builtin_amdgcn_s_barrier();                                                  \
  MFMA_C(b1r, 0, 1);                                                             \
  LOAD_A(AP, 1);                                                                 \
  __builtin_amdgcn_s_barrier();                                                  \
  stage_half<4>(B, SB, n0, KN, srow, schunk, dslot);                             \
  MFMA_C(b1r, 1, 1);                                                             \
  __builtin_amdgcn_s_barrier();                                                  \
  stage_half<MF>(A, SA, m0, KN, srow, schunk, dslot);                            \
  MFMA_C(b0r, 1, 0);                                                             \
  asm volatile("s_waitcnt vmcnt(%0)" :: "n"(VG) : "memory");                     \
  __builtin_amdgcn_s_barrier();

#define TILE_PLAIN(AP, BP)                                                       \
  LOAD_A(AP, 0); LOAD_B(b0r, BP, 0); LOAD_B(b1r, BP, 1);                         \
  __builtin_amdgcn_s_barrier();                                                  \
  MFMA_C(b0r, 0, 0);                                                             \
  __builtin_amdgcn_s_barrier();                                                  \
  MFMA_C(b1r, 0, 1);                                                             \
  LOAD_A(AP, 1);                                                                 \
  __builtin_amdgcn_s_barrier();                                                  \
  MFMA_C(b1r, 1, 1);                                                             \
  __builtin_amdgcn_s_barrier();                                                  \
  MFMA_C(b0r, 1, 0);

  for (int tt = 0; tt < 34; tt += 2) {
    TILE_STAGED(a0p, b0p, As[0], Bs[0], (tt + 2) * 64)
    TILE_STAGED(a1p, b1p, As[1], Bs[1], (tt + 3) * 64)
  }
  TILE_PLAIN(a0p, b0p)
  asm volatile("s_waitcnt vmcnt(0)" ::: "memory");
  __builtin_amdgcn_s_barrier();
  TILE_PLAIN(a1p, b1p)
#undef TILE_STAGED
#undef TILE_PLAIN
#undef LOAD_A
#undef LOAD_B
#undef MFMA_C

  if (EPI == 0) {
    const int mat = n0 / DIM;
    const int nb = n0 - mat * DIM;
    const float* bias = (mat == 0) ? b0 : (mat == 1) ? b1 : b2;
    __bf16* outp = (mat == 0) ? o0 : (mat == 1) ? o1 : o2;
#pragma unroll
    for (int mr = 0; mr < 2 * MF; ++mr) {
      const int gq = (m0 + wm * (MF * 32) + mr * 16) >> 4;
      const int si = gq * 4 + lg;
      const int pos3[3] = { si >> 8, (si >> 4) & 15, si & 15 };
#pragma unroll
      for (int p = 0; p < 2; ++p) {
        const int nlo = nb + wn * 64 + (2 * p) * 16 + lq;
        const int nhi = nlo + 16;
        const int hlo = nlo / HD, dlo = nlo - hlo * HD;
        const int hhi = nhi / HD, dhi = nhi - hhi * HD;
        const float blo = bias[nlo], bhi = bias[nhi];
        float c = 1.f, s = 0.f;
        if (mat < 2) {
          const int cix = dlo >> 5;
          const int toff = ((cix == 0) ? 0 : (cix == 1) ? 128 : 384) + pos3[cix] * 16 + lq;
          c = tcos[toff]; s = tsin[toff];
        }
#pragma unroll
        for (int r = 0; r < 4; ++r) {
          const int bp = lg * 4 + r;
          const float x1 = acc[mr][2 * p][r] + blo;
          const float x2 = acc[mr][2 * p + 1][r] + bhi;
          float y1 = x1, y2 = x2;
          if (mat < 2) { y1 = x1 * c - x2 * s; y2 = x2 * c + x1 * s; }
          outp[((size_t)(bp * NH + hlo) * SPS + gq) * HD + dlo] = (__bf16)y1;
          outp[((size_t)(bp * NH + hhi) * SPS + gq) * HD + dhi] = (__bf16)y2;
        }
      }
    }
  } else {
#pragma unroll
    for (int mr = 0; mr < 2 * MF; ++mr) {
      const int rbase = m0 + wm * (MF * 32) + mr * 16;
#pragma unroll
      for (int nr = 0; nr < 4; ++nr) {
        const int n = n0 + wn * 64 + nr * 16 + lq;
        const float bia = b0[n];
#pragma unroll
        for (int r = 0; r < 4; ++r)
          fout[(size_t)(rbase + lg * 4 + r) * DIM + n] = acc[mr][nr][r] + bia;
      }
    }
  }
}

// ---- V transpose: [b'h][g][d] -> [b'h][d][g], output PRE-SWIZZLED within each
//      64-key chunk (8-key group ^= d&7) so attn's linear global_load_lds lands
//      bank-conflict-free in LDS ----
__global__ __launch_bounds__(256) void transpose_v_kernel(
    const __bf16* __restrict__ v, __bf16* __restrict__ vT)
{
  __shared__ __bf16 t[96][72];   // [d][g ^ swz], row stride 144B
  const int tid = threadIdx.x, bid = blockIdx.x;
  const int bh = bid >> 3, g0 = (bid & 7) * 64;
  const __bf16* src = v + ((size_t)bh * SPS + g0) * HD;
#pragma unroll
  for (int it = 0; it < 3; ++it) {
    const int lin = it * 256 + tid;
    const int row = lin / 12, c8 = (lin % 12) * 8;
    bf16x8 x = *(const bf16x8*)(src + row * HD + c8);
#pragma unroll
    for (int j = 0; j < 8; ++j) {
      const int d = c8 + j;
      t[d][row ^ ((d & 7) << 3)] = x[j];
    }
  }
  __syncthreads();
  __bf16* dst = vT + (size_t)bh * HD * SPS + g0;
#pragma unroll
  for (int it = 0; it < 3; ++it) {
    const int lin = it * 256 + tid;
    const int d = lin / 8, gc = (lin % 8) * 8;
    bf16x8 o = *(const bf16x8*)&t[d][gc ^ ((d & 7) << 3)];
    *(bf16x8*)(dst + (size_t)d * SPS + (gc ^ ((d & 7) << 3))) = o;  // pre-swizzled out
  }
}

// ---- flash attention: 8 waves x 16 q-rows (128-q blocks), KVBLK=64, defer-max.
//      K and V double-buffered in LDS (linear gload16, V source pre-swizzled);
//      ONE barrier + ONE vmcnt(0) per tile: stage(t+1) at tile top (prior readers
//      of buf[1-cur] finished before last barrier), per-wave vmcnt(0) then barrier
//      at tile end makes all stages block-visible. 2 blocks/CU = 16 waves/CU. ----
__global__ __launch_bounds__(512, 2) void attn_kernel(
    const __bf16* __restrict__ q, const __bf16* __restrict__ k,
    const __bf16* __restrict__ vTs, __bf16* __restrict__ ao)
{
  __shared__ __align__(16) __bf16 Kt[2][64 * 96];  // [key][d] linear, 12KB each
  __shared__ __align__(16) __bf16 Vt[2][96 * 64];  // [d][key^swz], 12KB each
  __shared__ __bf16 Pl[8][16 * 72];                // per-wave P [q][key]
  const int tid = threadIdx.x;
  const int w = tid >> 6, l = tid & 63;
  const int lq = l & 15, lg = l >> 4;
  // 1536 blocks: chunked XCD swizzle, qt innermost (4 q-tiles of 128 per bh)
  const int bid = blockIdx.x;
  const int swz = (bid & 7) * 192 + (bid >> 3);
  const int qt = swz & 3;
  const int h  = (swz >> 2) % NH;
  const int bp = swz / (NH * 4);
  const size_t bh = (size_t)bp * NH + h;
  const __bf16* qb = q + bh * SPS * HD;
  const char* kbytes = (const char*)(k + bh * SPS * HD);
  const char* vbytes = (const char*)(vTs + bh * HD * SPS);
  bf16x8 qf[3];
  {
    const __bf16* qr = qb + (size_t)(qt * 128 + w * 16 + lq) * HD + lg * 8;
    qf[0] = *(const bf16x8*)(qr);
    qf[1] = *(const bf16x8*)(qr + 32);
    qf[2] = *(const bf16x8*)(qr + 64);
  }
  const float sc = 0.10206207261596575f * 1.4426950408889634f; // 96^-0.5 * log2(e)
  float m_run = -1e30f, l_run = 0.f;               // per-lane partial sum
  f32x4 o[6] = {};

  // staging: K tile = 12,288B contiguous at t*12288; V tile = 96 rows x 128B
  // (row stride 1024B) at col byte t*128. slot s -> dest byte s*16 (linear).
  // 512 threads: slots [0,512) all waves; slots [512,768) waves 0-3.
#define STAGE_TILE(tt, buf) do {                                                  \
    const int s0 = tid;                                                           \
    gload16(kbytes + (size_t)(tt) * 12288 + s0 * 16, (char*)&Kt[buf][0] + s0 * 16); \
    gload16(vbytes + (size_t)(s0 >> 3) * 1024 + (tt) * 128 + (s0 & 7) * 16,       \
            (char*)&Vt[buf][0] + s0 * 16);                                        \
    if (w < 4) {                                                                  \
      const int s1 = 512 + tid;                                                   \
      gload16(kbytes + (size_t)(tt) * 12288 + s1 * 16, (char*)&Kt[buf][0] + s1 * 16); \
      gload16(vbytes + (size_t)(s1 >> 3) * 1024 + (tt) * 128 + (s1 & 7) * 16,     \
              (char*)&Vt[buf][0] + s1 * 16);                                      \
    } } while (0)

  STAGE_TILE(0, 0);
  asm volatile("s_waitcnt vmcnt(0)" ::: "memory");
  __builtin_amdgcn_s_barrier();

  for (int t = 0; t < 8; ++t) {
    const int cur = t & 1;
    if (t < 7) STAGE_TILE(t + 1, 1 - cur);
    // ---- QK^T from Kt[cur]: S^T = K * Q^T (lane owns q = lq) ----
    f32x4 st[4];
    __builtin_amdgcn_s_setprio(1);
#pragma unroll
    for (int t2 = 0; t2 < 4; ++t2) {
      const __bf16* kr = &Kt[cur][(t2 * 16 + lq) * 96 + lg * 8];
      bf16x8 k0f = *(const bf16x8*)(kr);
      bf16x8 k1f = *(const bf16x8*)(kr + 32);
      bf16x8 k2f = *(const bf16x8*)(kr + 64);
      f32x4 s = {};
      s = __builtin_amdgcn_mfma_f32_16x16x32_bf16(k0f, qf[0], s, 0, 0, 0);
      s = __builtin_amdgcn_mfma_f32_16x16x32_bf16(k1f, qf[1], s, 0, 0, 0);
      s = __builtin_amdgcn_mfma_f32_16x16x32_bf16(k2f, qf[2], s, 0, 0, 0);
      st[t2] = s;
    }
    __builtin_amdgcn_s_setprio(0);
    // ---- online softmax, defer-max fast path ----
    float pmax = -1e30f;
#pragma unroll
    for (int t2 = 0; t2 < 4; ++t2)
#pragma unroll
      for (int r = 0; r < 4; ++r) pmax = fmaxf(pmax, st[t2][r]);
    pmax *= sc;
    if (__any(pmax > m_run + 8.f)) {               // rare: ~once per block
      float mn = fmaxf(m_run, pmax);
      mn = fmaxf(mn, __shfl_xor(mn, 16));
      mn = fmaxf(mn, __shfl_xor(mn, 32));
      const float alpha = exp2f(m_run - mn);
      l_run *= alpha;
      float al[4];
#pragma unroll
      for (int r = 0; r < 4; ++r) al[r] = __shfl(alpha, lg * 4 + r);
#pragma unroll
      for (int ni = 0; ni < 6; ++ni)
#pragma unroll
        for (int r = 0; r < 4; ++r) o[ni][r] *= al[r];
      m_run = mn;
    }
#pragma unroll
    for (int t2 = 0; t2 < 4; ++t2) {
      bf16x4 pb;
#pragma unroll
      for (int r = 0; r < 4; ++r) {
        const float p = exp2f(st[t2][r] * sc - m_run);  // bounded by 2^8
        l_run += p;
        pb[r] = (__bf16)p;
      }
      *(bf16x4*)&Pl[w][lq * 72 + t2 * 16 + lg * 4] = pb; // wave-private
    }
    // ---- PV from Vt[cur] (swizzled read); Pl same-wave (compiler lgkm waits) ----
#pragma unroll
    for (int ks = 0; ks < 2; ++ks) {
      bf16x8 pa = *(const bf16x8*)&Pl[w][lq * 72 + ks * 32 + lg * 8];
      __builtin_amdgcn_s_setprio(1);
#pragma unroll
      for (int ni = 0; ni < 6; ++ni) {
        const int col = (ks * 32 + lg * 8) ^ ((lq & 7) << 3);
        bf16x8 vf = *(const bf16x8*)&Vt[cur][(ni * 16 + lq) * 64 + col];
        o[ni] = __builtin_amdgcn_mfma_f32_16x16x32_bf16(pa, vf, o[ni], 0, 0, 0);
      }
      __builtin_amdgcn_s_setprio(0);
    }
    // tile end: own stage(t+1) landed, then block-wide visibility
    asm volatile("s_waitcnt vmcnt(0)" ::: "memory");
    __builtin_amdgcn_s_barrier();
  }
#undef STAGE_TILE
  l_run += __shfl_xor(l_run, 16);
  l_run += __shfl_xor(l_run, 32);
  float linv[4];
#pragma unroll
  for (int r = 0; r < 4; ++r) linv[r] = 1.f / __shfl(l_run, lg * 4 + r);
#pragma unroll
  for (int ni = 0; ni < 6; ++ni)
#pragma unroll
    for (int r = 0; r < 4; ++r) {
      const int gq = qt * 128 + w * 16 + lg * 4 + r;
      const int d = ni * 16 + lq;
      ao[(size_t)(gq * 16 + bp) * DIM + h * HD + d] = (__bf16)(o[ni][r] * linv[r]);
    }
}

extern "C" void kernel_launch(void* const* d_in, const int* in_sizes, int n_in,
                              void* d_out, int out_size, void* d_ws, size_t ws_size,
                              hipStream_t stream) {
  const float* hs = (const float*)d_in[0];
  const float* wq = (const float*)d_in[1];
  const float* bq = (const float*)d_in[2];
  const float* wk = (const float*)d_in[3];
  const float* bk = (const float*)d_in[4];
  const float* wv = (const float*)d_in[5];
  const float* bv = (const float*)d_in[6];
  const float* wo = (const float*)d_in[7];
  const float* bo = (const float*)d_in[8];
  float* out = (float*)d_out;

  char* ws = (char*)d_ws;
  // live-range-packed layout, total 193,462,272 bytes:
  __bf16* wqkvT = (__bf16*)(ws);                  // prep->qkv
  __bf16* hsb   = (__bf16*)(ws + 31850496);       // prep->qkv
  __bf16* qb    = (__bf16*)(ws + 69599232);       // qkv->attn
  __bf16* kbuf  = (__bf16*)(ws + 107347968);      // qkv->attn
  __bf16* vbuf  = (__bf16*)(ws + 145096704);      // qkv->transpose_v
  __bf16* woT   = (__bf16*)(ws + 182845440);      // prep->gemm_out
  __bf16* vbufT = (__bf16*)(ws);                  // transpose_v->attn (over wqkvT+hsb, dead)
  __bf16* ao    = vbuf;                           // attn->gemm_out (vbuf dead)

  prep_kernel<<<23616, 256, 0, stream>>>(hs, wq, wk, wv, wo, hsb, wqkvT, woT);
  gemm8p_kernel<0, 4, 0><<<768, 512, 0, stream>>>(hsb, wqkvT, bq, bk, bv, qb, kbuf, vbuf, nullptr);
  gemm8p_kernel<0, 2, 1><<<192, 512, 0, stream>>>(hsb, wqkvT, bq, bk, bv, qb, kbuf, vbuf, nullptr);
  transpose_v_kernel<<<3072, 256, 0, stream>>>(vbuf, vbufT);
  attn_kernel<<<1536, 512, 0, stream>>>(qb, kbuf, vbufT, ao);
  gemm8p_kernel<1, 2, 2><<<512, 512, 0, stream>>>(ao, woT, bo, nullptr, nullptr, nullptr, nullptr, nullptr, out);
  gemm8p_kernel<1, 1, 3><<<128, 512, 0, stream>>>(ao, woT, bo, nullptr, nullptr, nullptr, nullptr, nullptr, out);
}